// Round 6
// baseline (218.810 us; speedup 1.0000x reference)
//
#include <hip/hip_runtime.h>

typedef unsigned short u16;
typedef __bf16 bf16x8 __attribute__((ext_vector_type(8)));
typedef float f32x4 __attribute__((ext_vector_type(4)));
typedef float f32x16 __attribute__((ext_vector_type(16)));

static __device__ __forceinline__ u16 f2bf(float f) {
  unsigned u = __builtin_bit_cast(unsigned, f);
  u += 0x7fffu + ((u >> 16) & 1u);
  return (u16)(u >> 16);
}
static __device__ __forceinline__ float bf2f(u16 u) {
  return __builtin_bit_cast(float, (unsigned)u << 16);
}
// packed f32x2 -> bf16x2 (single VALU op)
static __device__ __forceinline__ unsigned cvtpk(float lo, float hi) {
  unsigned r;
  asm("v_cvt_pk_bf16_f32 %0, %1, %2" : "=v"(r) : "v"(lo), "v"(hi));
  return r;
}

static __device__ __forceinline__ void gload_lds16(const void* g, void* l) {
  __builtin_amdgcn_global_load_lds((const __attribute__((address_space(1))) unsigned int*)g,
                                   (__attribute__((address_space(3))) unsigned int*)l,
                                   16, 0, 0);
}

// ---------------------------------------------------------------------------
// fp32 -> bf16 conversion for X, Wq, Wk, Wv, Wo (one launch)
// ---------------------------------------------------------------------------
__global__ __launch_bounds__(256) void cvt_all(
    const float* __restrict__ X, const float* __restrict__ Wq, const float* __restrict__ Wk,
    const float* __restrict__ Wv, const float* __restrict__ Wo,
    u16* __restrict__ oX, u16* __restrict__ oWq, u16* __restrict__ oWk,
    u16* __restrict__ oWv, u16* __restrict__ oWo) {
  const int b = blockIdx.x;
  const float* s; u16* d; int lb;
  if (b < 1024)      { s = X;  d = oX;  lb = b; }
  else if (b < 2048) { s = Wq; d = oWq; lb = b - 1024; }
  else if (b < 2304) { s = Wk; d = oWk; lb = b - 2048; }
  else if (b < 2560) { s = Wv; d = oWv; lb = b - 2304; }
  else               { s = Wo; d = oWo; lb = b - 2560; }
  const int base = lb * 4096 + threadIdx.x * 4;
#pragma unroll
  for (int j = 0; j < 4; ++j) {
    const int off = base + j * 1024;
    float4 v = *(const float4*)(s + off);
    ushort4 u;
    u.x = f2bf(v.x); u.y = f2bf(v.y); u.z = f2bf(v.z); u.w = f2bf(v.w);
    *(ushort4*)(d + off) = u;
  }
}

// ---------------------------------------------------------------------------
// Fused QKV GEMM over virtual N=3072: [Wq | Wk | Wv], 128x128 tiles, BK=64.
// Q epilogue scale folds 1/sqrt(D) AND log2(e) (softmax runs in exp2 domain).
// ---------------------------------------------------------------------------
__global__ __launch_bounds__(256) void gemm_qkv(
    const u16* __restrict__ A, const u16* __restrict__ Bq, const u16* __restrict__ Bk,
    const u16* __restrict__ Bv, u16* __restrict__ Qb, u16* __restrict__ Kb,
    u16* __restrict__ Vt, const float* __restrict__ cosp, const float* __restrict__ sinp) {
  __shared__ u16 As[128 * 64];
  __shared__ u16 Bs[128 * 64];
  const int tid = threadIdx.x;
  const int lane = tid & 63, w = tid >> 6;
  const int wr = w >> 1, wc = w & 1;
  const int lr = lane & 15, lq = lane >> 4;
  const int bm = blockIdx.y << 7;
  const int bn = blockIdx.x << 7;
  const int K = 2048;

  const u16* Bp; int nb, region;
  if (bn < 2048)      { Bp = Bq; nb = bn;        region = 0; }
  else if (bn < 2560) { Bp = Bk; nb = bn - 2048; region = 1; }
  else                { Bp = Bv; nb = bn - 2560; region = 2; }

  f32x4 acc[4][4] = {};

  for (int kt = 0; kt < 32; ++kt) {
    const int k0 = kt << 6;
#pragma unroll
    for (int i = 0; i < 4; ++i) {
      const int seg = (i << 2) + w;
      const int idx = (seg << 6) + lane;
      const int r = idx >> 3, c = idx & 7;
      const int cs = (c ^ (r & 7)) << 3;
      gload_lds16(A + (size_t)(bm + r) * K + k0 + cs, (char*)As + seg * 1024);
      gload_lds16(Bp + (size_t)(nb + r) * K + k0 + cs, (char*)Bs + seg * 1024);
    }
    __syncthreads();
    bf16x8 af[2][4], bfv[2][4];
#pragma unroll
    for (int ks = 0; ks < 2; ++ks) {
#pragma unroll
      for (int f = 0; f < 4; ++f) {
        const int ra = wr * 64 + f * 16 + lr;
        const int ca = (lq + (ks << 2)) ^ (ra & 7);
        af[ks][f] = *(const bf16x8*)&As[((ra << 3) | ca) << 3];
        const int rb = wc * 64 + f * 16 + lr;
        const int cb = (lq + (ks << 2)) ^ (rb & 7);
        bfv[ks][f] = *(const bf16x8*)&Bs[((rb << 3) | cb) << 3];
      }
    }
#pragma unroll
    for (int ks = 0; ks < 2; ++ks)
#pragma unroll
      for (int mf = 0; mf < 4; ++mf)
#pragma unroll
        for (int nf = 0; nf < 4; ++nf)
          acc[mf][nf] = __builtin_amdgcn_mfma_f32_16x16x32_bf16(
              af[ks][mf], bfv[ks][nf], acc[mf][nf], 0, 0, 0);
    __syncthreads();
  }

  const int rbase = bm + wr * 64;
  const int cb64 = nb + wc * 64;
  if (region == 2) {
    const int hkv = cb64 >> 6;
#pragma unroll
    for (int mf = 0; mf < 4; ++mf) {
      const int s0 = rbase + mf * 16 + lq * 4;
#pragma unroll
      for (int nf = 0; nf < 4; ++nf) {
        const int d = (cb64 & 63) + nf * 16 + lr;
        ushort4 st;
        st.x = f2bf(acc[mf][nf][0]); st.y = f2bf(acc[mf][nf][1]);
        st.z = f2bf(acc[mf][nf][2]); st.w = f2bf(acc[mf][nf][3]);
        *(ushort4*)&Vt[(size_t)hkv * 131072 + (size_t)d * 2048 + s0] = st;
      }
    }
  } else {
    u16* outp = region ? Kb : Qb;
    const int ldo = region ? 512 : 2048;
    // Q: 1/8 * log2(e); K: 1.0
    const float post = region ? 1.0f : 0.18033688011112042f;
#pragma unroll
    for (int mf = 0; mf < 4; ++mf)
#pragma unroll
      for (int r = 0; r < 4; ++r) {
        const int s = rbase + mf * 16 + lq * 4 + r;
        const float* cr = cosp + s * 64;
        const float* sr = sinp + s * 64;
#pragma unroll
        for (int nf = 0; nf < 2; ++nf) {
          const int d1 = nf * 16 + lr, d2 = d1 + 32;
          const float x1 = acc[mf][nf][r], x2 = acc[mf][nf + 2][r];
          const float y1 = (x1 * cr[d1] - x2 * sr[d1]) * post;
          const float y2 = (x2 * cr[d2] + x1 * sr[d2]) * post;
          outp[(size_t)s * ldo + cb64 + d1] = f2bf(y1);
          outp[(size_t)s * ldo + cb64 + d2] = f2bf(y2);
        }
      }
  }
}

// ---------------------------------------------------------------------------
// out-proj GEMM (bf16 in, f32 out), 128x128 tile
// ---------------------------------------------------------------------------
__global__ __launch_bounds__(256) void gemm_out(
    const u16* __restrict__ A, const u16* __restrict__ B, float* __restrict__ C,
    int M, int N, int K) {
  __shared__ u16 As[128 * 64];
  __shared__ u16 Bs[128 * 64];
  const int tid = threadIdx.x;
  const int lane = tid & 63, w = tid >> 6;
  const int wr = w >> 1, wc = w & 1;
  const int lr = lane & 15, lq = lane >> 4;
  const int bm = blockIdx.y << 7, bn = blockIdx.x << 7;

  f32x4 acc[4][4] = {};
  const int nK = K >> 6;
  for (int kt = 0; kt < nK; ++kt) {
    const int k0 = kt << 6;
#pragma unroll
    for (int i = 0; i < 4; ++i) {
      const int seg = (i << 2) + w;
      const int idx = (seg << 6) + lane;
      const int r = idx >> 3, c = idx & 7;
      const int cs = (c ^ (r & 7)) << 3;
      gload_lds16(A + (size_t)(bm + r) * K + k0 + cs, (char*)As + seg * 1024);
      gload_lds16(B + (size_t)(bn + r) * K + k0 + cs, (char*)Bs + seg * 1024);
    }
    __syncthreads();
    bf16x8 af[2][4], bfv[2][4];
#pragma unroll
    for (int ks = 0; ks < 2; ++ks) {
#pragma unroll
      for (int f = 0; f < 4; ++f) {
        const int ra = wr * 64 + f * 16 + lr;
        const int ca = (lq + (ks << 2)) ^ (ra & 7);
        af[ks][f] = *(const bf16x8*)&As[((ra << 3) | ca) << 3];
        const int rb = wc * 64 + f * 16 + lr;
        const int cb = (lq + (ks << 2)) ^ (rb & 7);
        bfv[ks][f] = *(const bf16x8*)&Bs[((rb << 3) | cb) << 3];
      }
    }
#pragma unroll
    for (int ks = 0; ks < 2; ++ks)
#pragma unroll
      for (int mf = 0; mf < 4; ++mf)
#pragma unroll
        for (int nf = 0; nf < 4; ++nf)
          acc[mf][nf] = __builtin_amdgcn_mfma_f32_16x16x32_bf16(
              af[ks][mf], bfv[ks][nf], acc[mf][nf], 0, 0, 0);
    __syncthreads();
  }
  const int rbase = bm + wr * 64;
  const int cbase = bn + wc * 64;
#pragma unroll
  for (int mf = 0; mf < 4; ++mf)
#pragma unroll
    for (int r = 0; r < 4; ++r) {
      const int s = rbase + mf * 16 + lq * 4 + r;
#pragma unroll
      for (int nf = 0; nf < 4; ++nf)
        C[(size_t)s * N + cbase + nf * 16 + lr] = acc[mf][nf][r];
    }
}

// ---------------------------------------------------------------------------
// Attention v5: v3 structure (32-kv tiles, split-KV x2, K ping-pong prefetch,
// V issued at tile top) + log2-domain softmax accumulated in OLD-m scale with
// rescale AFTER PV (exact; rescale is linear). Max-tree/vote/l-shfl all off
// the critical path. setprio around MFMA clusters. No LDS, no barriers.
// ---------------------------------------------------------------------------
__global__ __launch_bounds__(256, 4) void attn_v5(
    const u16* __restrict__ Qb, const u16* __restrict__ Kb,
    const u16* __restrict__ Vt, u16* __restrict__ P0, u16* __restrict__ P1,
    float* __restrict__ ml) {
  const int hkv = blockIdx.y;
  const int qb = (hkv & 4) ? (63 - (int)blockIdx.x) : (int)blockIdx.x;
  const int chunk = blockIdx.z;
  const int w = threadIdx.x >> 6, lane = threadIdx.x & 63;
  const int col = lane & 31, hi = lane >> 5;
  const int g = col >> 3, r = col & 7;
  const int q0w = qb * 32 + w * 8;
  const int qg = q0w + r;
  const int h = hkv * 4 + g;

  const int nt = qb + 1;            // 32-kv tiles for this q block
  const int half = nt >> 1;
  const int t0 = chunk ? half : 0;
  const int t1 = chunk ? nt : half;

  const u16* qp = Qb + (size_t)qg * 2048 + h * 64 + hi * 8;
  uint4 qf[4];
#pragma unroll
  for (int s = 0; s < 4; ++s) qf[s] = *(const uint4*)(qp + 16 * s);

  const u16* Kp = Kb + (size_t)col * 512 + hkv * 64 + hi * 8;
  const u16* Vp = Vt + (size_t)hkv * 131072 + (size_t)col * 2048 + hi * 8;

  f32x16 o0 = {}, o1 = {};
  float m = 16.0f, l = 0.f;   // log2 domain; scores bounded << 16

  uint4 ka[4], kb_[4];

  auto loadK = [&](uint4 (&dst)[4], int t) {
    const u16* p = Kp + (size_t)(t << 5) * 512;
#pragma unroll
    for (int s = 0; s < 4; ++s) dst[s] = *(const uint4*)(p + 16 * s);  // +16s along d
  };

  auto body = [&](uint4 (&cur)[4], uint4 (&nxt)[4], int t) {
    const int kv0 = t << 5;
    // V loads for this tile (consumed after softmax) — issue first
    uint4 vf[4];
#pragma unroll
    for (int dt = 0; dt < 2; ++dt)
#pragma unroll
      for (int s = 0; s < 2; ++s)
        vf[dt * 2 + s] = *(const uint4*)(Vp + (size_t)dt * 65536 + kv0 + 16 * s);
    // prefetch K for next tile
    if (t + 1 < t1) loadK(nxt, t + 1);

    __builtin_amdgcn_s_setprio(1);
    f32x16 sc = {};
#pragma unroll
    for (int s = 0; s < 4; ++s)
      sc = __builtin_amdgcn_mfma_f32_32x32x16_bf16(
          __builtin_bit_cast(bf16x8, cur[s]), __builtin_bit_cast(bf16x8, qf[s]), sc, 0, 0, 0);
    __builtin_amdgcn_s_setprio(0);

    if (t == nt - 1) {  // diagonal tile mask
      const int qoff = w * 8 + r;
#pragma unroll
      for (int i = 0; i < 16; ++i) {
        const int kvr = (i & 3) + 8 * (i >> 2) + 4 * hi;
        if (kvr > qoff) sc[i] = -1e30f;
      }
    }

    // speculative exp in OLD-m scale (starts immediately after QK^T)
    float p[16];
#pragma unroll
    for (int i = 0; i < 16; ++i) p[i] = exp2f(sc[i] - m);

    // pack P (bf16) and feed PV — the only cross-lane op on the critical path
    unsigned W0[4], W1[4];
#pragma unroll
    for (int gg = 0; gg < 4; ++gg) {
      W0[gg] = cvtpk(p[4 * gg], p[4 * gg + 1]);
      W1[gg] = cvtpk(p[4 * gg + 2], p[4 * gg + 3]);
    }
    __builtin_amdgcn_s_setprio(1);
#pragma unroll
    for (int G = 0; G < 2; ++G) {
      const int ga = 2 * G, gb = 2 * G + 1;
      const unsigned s0 = hi ? W0[ga] : W0[gb];
      const unsigned s1 = hi ? W1[ga] : W1[gb];
      const unsigned r0_ = __shfl_xor(s0, 32, 64);
      const unsigned r1_ = __shfl_xor(s1, 32, 64);
      uint4 pw;
      pw.x = hi ? r0_ : W0[ga];
      pw.y = hi ? r1_ : W1[ga];
      pw.z = hi ? W0[gb] : r0_;
      pw.w = hi ? W1[gb] : r1_;
      const bf16x8 pf = __builtin_bit_cast(bf16x8, pw);
      o0 = __builtin_amdgcn_mfma_f32_32x32x16_bf16(
          __builtin_bit_cast(bf16x8, vf[G]), pf, o0, 0, 0, 0);
      o1 = __builtin_amdgcn_mfma_f32_32x32x16_bf16(
          __builtin_bit_cast(bf16x8, vf[2 + G]), pf, o1, 0, 0, 0);
    }
    __builtin_amdgcn_s_setprio(0);

    // l accumulation (off critical path)
    float r0 = 0.f, r1 = 0.f, r2 = 0.f, r3 = 0.f;
#pragma unroll
    for (int i = 0; i < 4; ++i) {
      r0 += p[4 * i];     r1 += p[4 * i + 1];
      r2 += p[4 * i + 2]; r3 += p[4 * i + 3];
    }
    float rs = (r0 + r1) + (r2 + r3);
    l += rs + __shfl_xor(rs, 32, 64);

    // max check AFTER accumulation; rescale is linear so this is exact
    float pa = fmaxf(fmaxf(sc[0], sc[1]), fmaxf(sc[2], sc[3]));
    float pb = fmaxf(fmaxf(sc[4], sc[5]), fmaxf(sc[6], sc[7]));
    float pc = fmaxf(fmaxf(sc[8], sc[9]), fmaxf(sc[10], sc[11]));
    float pd = fmaxf(fmaxf(sc[12], sc[13]), fmaxf(sc[14], sc[15]));
    float pm = fmaxf(fmaxf(pa, pb), fmaxf(pc, pd));
    pm = fmaxf(pm, __shfl_xor(pm, 32, 64));
    if (!__all(pm - m <= 8.0f)) {   // rare: convert o,l to new-m scale
      const float mn = fmaxf(m, pm);
      const float al = exp2f(m - mn);
      m = mn; l *= al;
#pragma unroll
      for (int i = 0; i < 16; ++i) { o0[i] *= al; o1[i] *= al; }
    }
  };

  int t = t0;
  if (t < t1) {
    loadK(ka, t);
    while (true) {
      body(ka, kb_, t); ++t; if (t >= t1) break;
      body(kb_, ka, t); ++t; if (t >= t1) break;
    }
  }

  // store unnormalized partials (bf16) + (m,l)
  u16* Pc = chunk ? P1 : P0;
  u16* op = Pc + (size_t)qg * 2048 + h * 64;
#pragma unroll
  for (int gg = 0; gg < 4; ++gg) {
    uint2 s0, s1;
    s0.x = cvtpk(o0[4 * gg], o0[4 * gg + 1]);
    s0.y = cvtpk(o0[4 * gg + 2], o0[4 * gg + 3]);
    s1.x = cvtpk(o1[4 * gg], o1[4 * gg + 1]);
    s1.y = cvtpk(o1[4 * gg + 2], o1[4 * gg + 3]);
    *(uint2*)(op + 8 * gg + 4 * hi)      = s0;
    *(uint2*)(op + 8 * gg + 4 * hi + 32) = s1;
  }
  if (hi == 0) {
    float* mlw = ml + (((size_t)chunk * 2048 + qg) * 32 + h) * 2;
    mlw[0] = m; mlw[1] = l;
  }
}

// ---------------------------------------------------------------------------
// merge the two KV-chunk partials -> ctx bf16 (log2-domain m)
// ---------------------------------------------------------------------------
__global__ __launch_bounds__(256) void attn_merge(
    const u16* __restrict__ P0, const u16* __restrict__ P1,
    const float* __restrict__ ml, u16* __restrict__ Cx) {
  const int s = blockIdx.x;
  const int e0 = threadIdx.x * 8;
  const int h = e0 >> 6;
  const float* mp = ml + ((size_t)s * 32 + h) * 2;
  const float m0 = mp[0], l0 = mp[1];
  const float m1 = mp[131072], l1 = mp[131073];
  const float M = fmaxf(m0, m1);
  float w0 = exp2f(m0 - M), w1 = exp2f(m1 - M);
  const float inv = 1.f / (l0 * w0 + l1 * w1);
  w0 *= inv; w1 *= inv;
  uint4 a = *(const uint4*)(P0 + (size_t)s * 2048 + e0);
  uint4 b = *(const uint4*)(P1 + (size_t)s * 2048 + e0);
  const u16* pa = (const u16*)&a;
  const u16* pb = (const u16*)&b;
  ushort4 oA, oB;
  oA.x = f2bf(bf2f(pa[0]) * w0 + bf2f(pb[0]) * w1);
  oA.y = f2bf(bf2f(pa[1]) * w0 + bf2f(pb[1]) * w1);
  oA.z = f2bf(bf2f(pa[2]) * w0 + bf2f(pb[2]) * w1);
  oA.w = f2bf(bf2f(pa[3]) * w0 + bf2f(pb[3]) * w1);
  oB.x = f2bf(bf2f(pa[4]) * w0 + bf2f(pb[4]) * w1);
  oB.y = f2bf(bf2f(pa[5]) * w0 + bf2f(pb[5]) * w1);
  oB.z = f2bf(bf2f(pa[6]) * w0 + bf2f(pb[6]) * w1);
  oB.w = f2bf(bf2f(pa[7]) * w0 + bf2f(pb[7]) * w1);
  *(ushort4*)(Cx + (size_t)s * 2048 + e0)     = oA;
  *(ushort4*)(Cx + (size_t)s * 2048 + e0 + 4) = oB;
}

// ---------------------------------------------------------------------------
extern "C" void kernel_launch(void* const* d_in, const int* in_sizes, int n_in,
                              void* d_out, int out_size, void* d_ws, size_t ws_size,
                              hipStream_t stream) {
  const float* X    = (const float*)d_in[0];
  const float* cosp = (const float*)d_in[1];
  const float* sinp = (const float*)d_in[2];
  const float* Wq   = (const float*)d_in[3];
  const float* Wk   = (const float*)d_in[4];
  const float* Wv   = (const float*)d_in[5];
  const float* Wo   = (const float*)d_in[6];

  u16* ws  = (u16*)d_ws;
  u16* Xb  = ws;                         // 2048x2048 (later reused as P0)
  u16* Wqb = ws + 4194304;               // 2048x2048 (later reused as P1)
  u16* Wkb = ws + 8388608;               // 512x2048  (later reused as ml)
  u16* Wvb = ws + 9437184;               // 512x2048
  u16* Wob = ws + 10485760;              // 2048x2048
  u16* Qb  = ws + 14680064;              // 2048x2048 (rope'd, *log2e/8)
  u16* Kb  = ws + 18874368;              // 2048x512  (rope'd)
  u16* Vt  = ws + 19922944;              // 8x64x2048 (V transposed per head)
  u16* Cx  = ws + 20971520;              // 2048x2048 ctx
  u16* P0  = Xb;
  u16* P1  = Wqb;
  float* ml = (float*)(ws + 8388608);

  cvt_all<<<3584, 256, 0, stream>>>(X, Wq, Wk, Wv, Wo, Xb, Wqb, Wkb, Wvb, Wob);

  dim3 gqkv(24, 16), ga(64, 8, 2), go(16, 16);
  gemm_qkv<<<gqkv, 256, 0, stream>>>(Xb, Wqb, Wkb, Wvb, Qb, Kb, Vt, cosp, sinp);
  attn_v5<<<ga, 256, 0, stream>>>(Qb, Kb, Vt, P0, P1, ml);
  attn_merge<<<2048, 256, 0, stream>>>(P0, P1, ml, Cx);
  gemm_out<<<go, 256, 0, stream>>>(Cx, Wob, (float*)d_out, 2048, 2048, 2048);
}

// Round 7
// 175.908 us; speedup vs baseline: 1.2439x; 1.2439x over previous
//
#include <hip/hip_runtime.h>

typedef unsigned short u16;
typedef __bf16 bf16x8 __attribute__((ext_vector_type(8)));
typedef float f32x4 __attribute__((ext_vector_type(4)));
typedef float f32x16 __attribute__((ext_vector_type(16)));

static __device__ __forceinline__ u16 f2bf(float f) {
  unsigned u = __builtin_bit_cast(unsigned, f);
  u += 0x7fffu + ((u >> 16) & 1u);
  return (u16)(u >> 16);
}
static __device__ __forceinline__ float bf2f(u16 u) {
  return __builtin_bit_cast(float, (unsigned)u << 16);
}
// packed f32x2 -> bf16x2 (single VALU op)
static __device__ __forceinline__ unsigned cvtpk(float lo, float hi) {
  unsigned r;
  asm("v_cvt_pk_bf16_f32 %0, %1, %2" : "=v"(r) : "v"(lo), "v"(hi));
  return r;
}

static __device__ __forceinline__ void gload_lds16(const void* g, void* l) {
  __builtin_amdgcn_global_load_lds((const __attribute__((address_space(1))) unsigned int*)g,
                                   (__attribute__((address_space(3))) unsigned int*)l,
                                   16, 0, 0);
}

// ---------------------------------------------------------------------------
// fp32 -> bf16 conversion for X, Wq, Wk, Wv, Wo (one launch)
// ---------------------------------------------------------------------------
__global__ __launch_bounds__(256) void cvt_all(
    const float* __restrict__ X, const float* __restrict__ Wq, const float* __restrict__ Wk,
    const float* __restrict__ Wv, const float* __restrict__ Wo,
    u16* __restrict__ oX, u16* __restrict__ oWq, u16* __restrict__ oWk,
    u16* __restrict__ oWv, u16* __restrict__ oWo) {
  const int b = blockIdx.x;
  const float* s; u16* d; int lb;
  if (b < 1024)      { s = X;  d = oX;  lb = b; }
  else if (b < 2048) { s = Wq; d = oWq; lb = b - 1024; }
  else if (b < 2304) { s = Wk; d = oWk; lb = b - 2048; }
  else if (b < 2560) { s = Wv; d = oWv; lb = b - 2304; }
  else               { s = Wo; d = oWo; lb = b - 2560; }
  const int base = lb * 4096 + threadIdx.x * 4;
#pragma unroll
  for (int j = 0; j < 4; ++j) {
    const int off = base + j * 1024;
    float4 v = *(const float4*)(s + off);
    ushort4 u;
    u.x = f2bf(v.x); u.y = f2bf(v.y); u.z = f2bf(v.z); u.w = f2bf(v.w);
    *(ushort4*)(d + off) = u;
  }
}

// ---------------------------------------------------------------------------
// Fused QKV GEMM over virtual N=3072: [Wq | Wk | Wv], 128x128 tiles, BK=64.
// Q epilogue scale folds 1/sqrt(D) AND log2(e) (softmax runs in exp2 domain).
// ---------------------------------------------------------------------------
__global__ __launch_bounds__(256) void gemm_qkv(
    const u16* __restrict__ A, const u16* __restrict__ Bq, const u16* __restrict__ Bk,
    const u16* __restrict__ Bv, u16* __restrict__ Qb, u16* __restrict__ Kb,
    u16* __restrict__ Vt, const float* __restrict__ cosp, const float* __restrict__ sinp) {
  __shared__ u16 As[128 * 64];
  __shared__ u16 Bs[128 * 64];
  const int tid = threadIdx.x;
  const int lane = tid & 63, w = tid >> 6;
  const int wr = w >> 1, wc = w & 1;
  const int lr = lane & 15, lq = lane >> 4;
  const int bm = blockIdx.y << 7;
  const int bn = blockIdx.x << 7;
  const int K = 2048;

  const u16* Bp; int nb, region;
  if (bn < 2048)      { Bp = Bq; nb = bn;        region = 0; }
  else if (bn < 2560) { Bp = Bk; nb = bn - 2048; region = 1; }
  else                { Bp = Bv; nb = bn - 2560; region = 2; }

  f32x4 acc[4][4] = {};

  for (int kt = 0; kt < 32; ++kt) {
    const int k0 = kt << 6;
#pragma unroll
    for (int i = 0; i < 4; ++i) {
      const int seg = (i << 2) + w;
      const int idx = (seg << 6) + lane;
      const int r = idx >> 3, c = idx & 7;
      const int cs = (c ^ (r & 7)) << 3;
      gload_lds16(A + (size_t)(bm + r) * K + k0 + cs, (char*)As + seg * 1024);
      gload_lds16(Bp + (size_t)(nb + r) * K + k0 + cs, (char*)Bs + seg * 1024);
    }
    __syncthreads();
    bf16x8 af[2][4], bfv[2][4];
#pragma unroll
    for (int ks = 0; ks < 2; ++ks) {
#pragma unroll
      for (int f = 0; f < 4; ++f) {
        const int ra = wr * 64 + f * 16 + lr;
        const int ca = (lq + (ks << 2)) ^ (ra & 7);
        af[ks][f] = *(const bf16x8*)&As[((ra << 3) | ca) << 3];
        const int rb = wc * 64 + f * 16 + lr;
        const int cb = (lq + (ks << 2)) ^ (rb & 7);
        bfv[ks][f] = *(const bf16x8*)&Bs[((rb << 3) | cb) << 3];
      }
    }
#pragma unroll
    for (int ks = 0; ks < 2; ++ks)
#pragma unroll
      for (int mf = 0; mf < 4; ++mf)
#pragma unroll
        for (int nf = 0; nf < 4; ++nf)
          acc[mf][nf] = __builtin_amdgcn_mfma_f32_16x16x32_bf16(
              af[ks][mf], bfv[ks][nf], acc[mf][nf], 0, 0, 0);
    __syncthreads();
  }

  const int rbase = bm + wr * 64;
  const int cb64 = nb + wc * 64;
  if (region == 2) {
    const int hkv = cb64 >> 6;
#pragma unroll
    for (int mf = 0; mf < 4; ++mf) {
      const int s0 = rbase + mf * 16 + lq * 4;
#pragma unroll
      for (int nf = 0; nf < 4; ++nf) {
        const int d = (cb64 & 63) + nf * 16 + lr;
        ushort4 st;
        st.x = f2bf(acc[mf][nf][0]); st.y = f2bf(acc[mf][nf][1]);
        st.z = f2bf(acc[mf][nf][2]); st.w = f2bf(acc[mf][nf][3]);
        *(ushort4*)&Vt[(size_t)hkv * 131072 + (size_t)d * 2048 + s0] = st;
      }
    }
  } else {
    u16* outp = region ? Kb : Qb;
    const int ldo = region ? 512 : 2048;
    // Q: 1/8 * log2(e); K: 1.0
    const float post = region ? 1.0f : 0.18033688011112042f;
#pragma unroll
    for (int mf = 0; mf < 4; ++mf)
#pragma unroll
      for (int r = 0; r < 4; ++r) {
        const int s = rbase + mf * 16 + lq * 4 + r;
        const float* cr = cosp + s * 64;
        const float* sr = sinp + s * 64;
#pragma unroll
        for (int nf = 0; nf < 2; ++nf) {
          const int d1 = nf * 16 + lr, d2 = d1 + 32;
          const float x1 = acc[mf][nf][r], x2 = acc[mf][nf + 2][r];
          const float y1 = (x1 * cr[d1] - x2 * sr[d1]) * post;
          const float y2 = (x2 * cr[d2] + x1 * sr[d2]) * post;
          outp[(size_t)s * ldo + cb64 + d1] = f2bf(y1);
          outp[(size_t)s * ldo + cb64 + d2] = f2bf(y2);
        }
      }
  }
}

// ---------------------------------------------------------------------------
// out-proj GEMM (bf16 in, f32 out), 128x128 tile
// ---------------------------------------------------------------------------
__global__ __launch_bounds__(256) void gemm_out(
    const u16* __restrict__ A, const u16* __restrict__ B, float* __restrict__ C,
    int M, int N, int K) {
  __shared__ u16 As[128 * 64];
  __shared__ u16 Bs[128 * 64];
  const int tid = threadIdx.x;
  const int lane = tid & 63, w = tid >> 6;
  const int wr = w >> 1, wc = w & 1;
  const int lr = lane & 15, lq = lane >> 4;
  const int bm = blockIdx.y << 7, bn = blockIdx.x << 7;

  f32x4 acc[4][4] = {};
  const int nK = K >> 6;
  for (int kt = 0; kt < nK; ++kt) {
    const int k0 = kt << 6;
#pragma unroll
    for (int i = 0; i < 4; ++i) {
      const int seg = (i << 2) + w;
      const int idx = (seg << 6) + lane;
      const int r = idx >> 3, c = idx & 7;
      const int cs = (c ^ (r & 7)) << 3;
      gload_lds16(A + (size_t)(bm + r) * K + k0 + cs, (char*)As + seg * 1024);
      gload_lds16(B + (size_t)(bn + r) * K + k0 + cs, (char*)Bs + seg * 1024);
    }
    __syncthreads();
    bf16x8 af[2][4], bfv[2][4];
#pragma unroll
    for (int ks = 0; ks < 2; ++ks) {
#pragma unroll
      for (int f = 0; f < 4; ++f) {
        const int ra = wr * 64 + f * 16 + lr;
        const int ca = (lq + (ks << 2)) ^ (ra & 7);
        af[ks][f] = *(const bf16x8*)&As[((ra << 3) | ca) << 3];
        const int rb = wc * 64 + f * 16 + lr;
        const int cb = (lq + (ks << 2)) ^ (rb & 7);
        bfv[ks][f] = *(const bf16x8*)&Bs[((rb << 3) | cb) << 3];
      }
    }
#pragma unroll
    for (int ks = 0; ks < 2; ++ks)
#pragma unroll
      for (int mf = 0; mf < 4; ++mf)
#pragma unroll
        for (int nf = 0; nf < 4; ++nf)
          acc[mf][nf] = __builtin_amdgcn_mfma_f32_16x16x32_bf16(
              af[ks][mf], bfv[ks][nf], acc[mf][nf], 0, 0, 0);
    __syncthreads();
  }
  const int rbase = bm + wr * 64;
  const int cbase = bn + wc * 64;
#pragma unroll
  for (int mf = 0; mf < 4; ++mf)
#pragma unroll
    for (int r = 0; r < 4; ++r) {
      const int s = rbase + mf * 16 + lq * 4 + r;
#pragma unroll
      for (int nf = 0; nf < 4; ++nf)
        C[(size_t)s * N + cbase + nf * 16 + lr] = acc[mf][nf][r];
    }
}

// ---------------------------------------------------------------------------
// Attention v6: v3 structure (32-kv tiles, split-KV x2, K ping-pong prefetch,
// V issued at tile top) with NO running max at all: scores are Cauchy-Schwarz
// bounded (|sc| <= ~9.5 in log2 units), so p = exp2(sc) is exact softmax after
// the final o/l normalization; masked lanes give exp2(-1e30) = 0. Partials
// share an absolute scale -> merge is (o0+o1)/(l0+l1). Only cross-lane ops per
// tile: the 2 pack exchanges feeding PV. l accumulates lane-locally; one shfl
// at the end. sc dies at exp (v3's no-spill liveness profile).
// ---------------------------------------------------------------------------
__global__ __launch_bounds__(256, 4) void attn_v6(
    const u16* __restrict__ Qb, const u16* __restrict__ Kb,
    const u16* __restrict__ Vt, u16* __restrict__ P0, u16* __restrict__ P1,
    float* __restrict__ lsum) {
  const int hkv = blockIdx.y;
  const int qb = (hkv & 4) ? (63 - (int)blockIdx.x) : (int)blockIdx.x;
  const int chunk = blockIdx.z;
  const int w = threadIdx.x >> 6, lane = threadIdx.x & 63;
  const int col = lane & 31, hi = lane >> 5;
  const int g = col >> 3, r = col & 7;
  const int q0w = qb * 32 + w * 8;
  const int qg = q0w + r;
  const int h = hkv * 4 + g;

  const int nt = qb + 1;            // 32-kv tiles for this q block
  const int half = nt >> 1;
  const int t0 = chunk ? half : 0;
  const int t1 = chunk ? nt : half;

  const u16* qp = Qb + (size_t)qg * 2048 + h * 64 + hi * 8;
  uint4 qf[4];
#pragma unroll
  for (int s = 0; s < 4; ++s) qf[s] = *(const uint4*)(qp + 16 * s);

  const u16* Kp = Kb + (size_t)col * 512 + hkv * 64 + hi * 8;
  const u16* Vp = Vt + (size_t)hkv * 131072 + (size_t)col * 2048 + hi * 8;

  f32x16 o0 = {}, o1 = {};
  float l_loc = 0.f;

  uint4 ka[4], kb_[4];

  auto loadK = [&](uint4 (&dst)[4], int t) {
    const u16* p = Kp + (size_t)(t << 5) * 512;
#pragma unroll
    for (int s = 0; s < 4; ++s) dst[s] = *(const uint4*)(p + 16 * s);  // +16s along d
  };

  auto body = [&](uint4 (&cur)[4], uint4 (&nxt)[4], int t) {
    const int kv0 = t << 5;
    // V loads for this tile (consumed after softmax) — issue first
    uint4 vf[4];
#pragma unroll
    for (int dt = 0; dt < 2; ++dt)
#pragma unroll
      for (int s = 0; s < 2; ++s)
        vf[dt * 2 + s] = *(const uint4*)(Vp + (size_t)dt * 65536 + kv0 + 16 * s);
    // prefetch K for next tile
    if (t + 1 < t1) loadK(nxt, t + 1);

    __builtin_amdgcn_s_setprio(1);
    f32x16 sc = {};
#pragma unroll
    for (int s = 0; s < 4; ++s)
      sc = __builtin_amdgcn_mfma_f32_32x32x16_bf16(
          __builtin_bit_cast(bf16x8, cur[s]), __builtin_bit_cast(bf16x8, qf[s]), sc, 0, 0, 0);
    __builtin_amdgcn_s_setprio(0);

    if (t == nt - 1) {  // diagonal tile mask
      const int qoff = w * 8 + r;
#pragma unroll
      for (int i = 0; i < 16; ++i) {
        const int kvr = (i & 3) + 8 * (i >> 2) + 4 * hi;
        if (kvr > qoff) sc[i] = -1e30f;
      }
    }

    // absolute-scale p (no max subtraction); sc dies here
    float p[16];
#pragma unroll
    for (int i = 0; i < 16; ++i) p[i] = exp2f(sc[i]);

    // l accumulation (lane-local, no shfl in loop)
    float r0 = 0.f, r1 = 0.f, r2 = 0.f, r3 = 0.f;
#pragma unroll
    for (int i = 0; i < 4; ++i) {
      r0 += p[4 * i];     r1 += p[4 * i + 1];
      r2 += p[4 * i + 2]; r3 += p[4 * i + 3];
    }
    l_loc += (r0 + r1) + (r2 + r3);

    // pack P (bf16); p dies here
    unsigned W0[4], W1[4];
#pragma unroll
    for (int gg = 0; gg < 4; ++gg) {
      W0[gg] = cvtpk(p[4 * gg], p[4 * gg + 1]);
      W1[gg] = cvtpk(p[4 * gg + 2], p[4 * gg + 3]);
    }
    __builtin_amdgcn_s_setprio(1);
#pragma unroll
    for (int G = 0; G < 2; ++G) {
      const int ga = 2 * G, gb = 2 * G + 1;
      const unsigned s0 = hi ? W0[ga] : W0[gb];
      const unsigned s1 = hi ? W1[ga] : W1[gb];
      const unsigned r0_ = __shfl_xor(s0, 32, 64);
      const unsigned r1_ = __shfl_xor(s1, 32, 64);
      uint4 pw;
      pw.x = hi ? r0_ : W0[ga];
      pw.y = hi ? r1_ : W1[ga];
      pw.z = hi ? W0[gb] : r0_;
      pw.w = hi ? W1[gb] : r1_;
      const bf16x8 pf = __builtin_bit_cast(bf16x8, pw);
      o0 = __builtin_amdgcn_mfma_f32_32x32x16_bf16(
          __builtin_bit_cast(bf16x8, vf[G]), pf, o0, 0, 0, 0);
      o1 = __builtin_amdgcn_mfma_f32_32x32x16_bf16(
          __builtin_bit_cast(bf16x8, vf[2 + G]), pf, o1, 0, 0, 0);
    }
    __builtin_amdgcn_s_setprio(0);
  };

  int t = t0;
  if (t < t1) {
    loadK(ka, t);
    while (true) {
      body(ka, kb_, t); ++t; if (t >= t1) break;
      body(kb_, ka, t); ++t; if (t >= t1) break;
    }
  }

  const float l = l_loc + __shfl_xor(l_loc, 32, 64);

  // store unnormalized partials (bf16) + l
  u16* Pc = chunk ? P1 : P0;
  u16* op = Pc + (size_t)qg * 2048 + h * 64;
#pragma unroll
  for (int gg = 0; gg < 4; ++gg) {
    uint2 s0, s1;
    s0.x = cvtpk(o0[4 * gg], o0[4 * gg + 1]);
    s0.y = cvtpk(o0[4 * gg + 2], o0[4 * gg + 3]);
    s1.x = cvtpk(o1[4 * gg], o1[4 * gg + 1]);
    s1.y = cvtpk(o1[4 * gg + 2], o1[4 * gg + 3]);
    *(uint2*)(op + 8 * gg + 4 * hi)      = s0;
    *(uint2*)(op + 8 * gg + 4 * hi + 32) = s1;
  }
  if (hi == 0)
    lsum[(size_t)chunk * 65536 + (size_t)qg * 32 + h] = l;
}

// ---------------------------------------------------------------------------
// merge the two KV-chunk partials -> ctx bf16 (absolute scale: o/(l0+l1))
// ---------------------------------------------------------------------------
__global__ __launch_bounds__(256) void attn_merge(
    const u16* __restrict__ P0, const u16* __restrict__ P1,
    const float* __restrict__ lsum, u16* __restrict__ Cx) {
  const int s = blockIdx.x;
  const int e0 = threadIdx.x * 8;
  const int h = e0 >> 6;
  const float l0 = lsum[(size_t)s * 32 + h];
  const float l1 = lsum[65536 + (size_t)s * 32 + h];
  const float inv = 1.f / (l0 + l1);
  uint4 a = *(const uint4*)(P0 + (size_t)s * 2048 + e0);
  uint4 b = *(const uint4*)(P1 + (size_t)s * 2048 + e0);
  const u16* pa = (const u16*)&a;
  const u16* pb = (const u16*)&b;
  ushort4 oA, oB;
  oA.x = f2bf((bf2f(pa[0]) + bf2f(pb[0])) * inv);
  oA.y = f2bf((bf2f(pa[1]) + bf2f(pb[1])) * inv);
  oA.z = f2bf((bf2f(pa[2]) + bf2f(pb[2])) * inv);
  oA.w = f2bf((bf2f(pa[3]) + bf2f(pb[3])) * inv);
  oB.x = f2bf((bf2f(pa[4]) + bf2f(pb[4])) * inv);
  oB.y = f2bf((bf2f(pa[5]) + bf2f(pb[5])) * inv);
  oB.z = f2bf((bf2f(pa[6]) + bf2f(pb[6])) * inv);
  oB.w = f2bf((bf2f(pa[7]) + bf2f(pb[7])) * inv);
  *(ushort4*)(Cx + (size_t)s * 2048 + e0)     = oA;
  *(ushort4*)(Cx + (size_t)s * 2048 + e0 + 4) = oB;
}

// ---------------------------------------------------------------------------
extern "C" void kernel_launch(void* const* d_in, const int* in_sizes, int n_in,
                              void* d_out, int out_size, void* d_ws, size_t ws_size,
                              hipStream_t stream) {
  const float* X    = (const float*)d_in[0];
  const float* cosp = (const float*)d_in[1];
  const float* sinp = (const float*)d_in[2];
  const float* Wq   = (const float*)d_in[3];
  const float* Wk   = (const float*)d_in[4];
  const float* Wv   = (const float*)d_in[5];
  const float* Wo   = (const float*)d_in[6];

  u16* ws  = (u16*)d_ws;
  u16* Xb  = ws;                         // 2048x2048 (later reused as P0)
  u16* Wqb = ws + 4194304;               // 2048x2048 (later reused as P1)
  u16* Wkb = ws + 8388608;               // 512x2048  (later reused as lsum)
  u16* Wvb = ws + 9437184;               // 512x2048
  u16* Wob = ws + 10485760;              // 2048x2048
  u16* Qb  = ws + 14680064;              // 2048x2048 (rope'd, *log2e/8)
  u16* Kb  = ws + 18874368;              // 2048x512  (rope'd)
  u16* Vt  = ws + 19922944;              // 8x64x2048 (V transposed per head)
  u16* Cx  = ws + 20971520;              // 2048x2048 ctx
  u16* P0  = Xb;
  u16* P1  = Wqb;
  float* lsum = (float*)(ws + 8388608);

  cvt_all<<<3584, 256, 0, stream>>>(X, Wq, Wk, Wv, Wo, Xb, Wqb, Wkb, Wvb, Wob);

  dim3 gqkv(24, 16), ga(64, 8, 2), go(16, 16);
  gemm_qkv<<<gqkv, 256, 0, stream>>>(Xb, Wqb, Wkb, Wvb, Qb, Kb, Vt, cosp, sinp);
  attn_v6<<<ga, 256, 0, stream>>>(Qb, Kb, Vt, P0, P1, lsum);
  attn_merge<<<2048, 256, 0, stream>>>(P0, P1, lsum, Cx);
  gemm_out<<<go, 256, 0, stream>>>(Cx, Wob, (float*)d_out, 2048, 2048, 2048);
}

// Round 8
// 145.685 us; speedup vs baseline: 1.5019x; 1.2075x over previous
//
#include <hip/hip_runtime.h>

typedef unsigned short u16;
typedef __bf16 bf16x8 __attribute__((ext_vector_type(8)));
typedef float f32x4 __attribute__((ext_vector_type(4)));
typedef float f32x16 __attribute__((ext_vector_type(16)));

static __device__ __forceinline__ u16 f2bf(float f) {
  unsigned u = __builtin_bit_cast(unsigned, f);
  u += 0x7fffu + ((u >> 16) & 1u);
  return (u16)(u >> 16);
}
static __device__ __forceinline__ float bf2f(u16 u) {
  return __builtin_bit_cast(float, (unsigned)u << 16);
}
// packed f32x2 -> bf16x2 (single VALU op)
static __device__ __forceinline__ unsigned cvtpk(float lo, float hi) {
  unsigned r;
  asm("v_cvt_pk_bf16_f32 %0, %1, %2" : "=v"(r) : "v"(lo), "v"(hi));
  return r;
}

static __device__ __forceinline__ void gload_lds16(const void* g, void* l) {
  __builtin_amdgcn_global_load_lds((const __attribute__((address_space(1))) unsigned int*)g,
                                   (__attribute__((address_space(3))) unsigned int*)l,
                                   16, 0, 0);
}

// ---------------------------------------------------------------------------
// fp32 -> bf16 conversion for X, Wq, Wk, Wv, Wo (one launch)
// ---------------------------------------------------------------------------
__global__ __launch_bounds__(256) void cvt_all(
    const float* __restrict__ X, const float* __restrict__ Wq, const float* __restrict__ Wk,
    const float* __restrict__ Wv, const float* __restrict__ Wo,
    u16* __restrict__ oX, u16* __restrict__ oWq, u16* __restrict__ oWk,
    u16* __restrict__ oWv, u16* __restrict__ oWo) {
  const int b = blockIdx.x;
  const float* s; u16* d; int lb;
  if (b < 1024)      { s = X;  d = oX;  lb = b; }
  else if (b < 2048) { s = Wq; d = oWq; lb = b - 1024; }
  else if (b < 2304) { s = Wk; d = oWk; lb = b - 2048; }
  else if (b < 2560) { s = Wv; d = oWv; lb = b - 2304; }
  else               { s = Wo; d = oWo; lb = b - 2560; }
  const int base = lb * 4096 + threadIdx.x * 4;
#pragma unroll
  for (int j = 0; j < 4; ++j) {
    const int off = base + j * 1024;
    float4 v = *(const float4*)(s + off);
    ushort4 u;
    u.x = f2bf(v.x); u.y = f2bf(v.y); u.z = f2bf(v.z); u.w = f2bf(v.w);
    *(ushort4*)(d + off) = u;
  }
}

// ---------------------------------------------------------------------------
// Fused QKV GEMM over virtual N=3072: [Wq | Wk | Wv], 128x128 tiles, BK=64.
// Q epilogue scale folds 1/sqrt(D) AND log2(e) (softmax runs in exp2 domain).
// ---------------------------------------------------------------------------
__global__ __launch_bounds__(256) void gemm_qkv(
    const u16* __restrict__ A, const u16* __restrict__ Bq, const u16* __restrict__ Bk,
    const u16* __restrict__ Bv, u16* __restrict__ Qb, u16* __restrict__ Kb,
    u16* __restrict__ Vt, const float* __restrict__ cosp, const float* __restrict__ sinp) {
  __shared__ u16 As[128 * 64];
  __shared__ u16 Bs[128 * 64];
  const int tid = threadIdx.x;
  const int lane = tid & 63, w = tid >> 6;
  const int wr = w >> 1, wc = w & 1;
  const int lr = lane & 15, lq = lane >> 4;
  const int bm = blockIdx.y << 7;
  const int bn = blockIdx.x << 7;
  const int K = 2048;

  const u16* Bp; int nb, region;
  if (bn < 2048)      { Bp = Bq; nb = bn;        region = 0; }
  else if (bn < 2560) { Bp = Bk; nb = bn - 2048; region = 1; }
  else                { Bp = Bv; nb = bn - 2560; region = 2; }

  f32x4 acc[4][4] = {};

  for (int kt = 0; kt < 32; ++kt) {
    const int k0 = kt << 6;
#pragma unroll
    for (int i = 0; i < 4; ++i) {
      const int seg = (i << 2) + w;
      const int idx = (seg << 6) + lane;
      const int r = idx >> 3, c = idx & 7;
      const int cs = (c ^ (r & 7)) << 3;
      gload_lds16(A + (size_t)(bm + r) * K + k0 + cs, (char*)As + seg * 1024);
      gload_lds16(Bp + (size_t)(nb + r) * K + k0 + cs, (char*)Bs + seg * 1024);
    }
    __syncthreads();
    bf16x8 af[2][4], bfv[2][4];
#pragma unroll
    for (int ks = 0; ks < 2; ++ks) {
#pragma unroll
      for (int f = 0; f < 4; ++f) {
        const int ra = wr * 64 + f * 16 + lr;
        const int ca = (lq + (ks << 2)) ^ (ra & 7);
        af[ks][f] = *(const bf16x8*)&As[((ra << 3) | ca) << 3];
        const int rb = wc * 64 + f * 16 + lr;
        const int cb = (lq + (ks << 2)) ^ (rb & 7);
        bfv[ks][f] = *(const bf16x8*)&Bs[((rb << 3) | cb) << 3];
      }
    }
#pragma unroll
    for (int ks = 0; ks < 2; ++ks)
#pragma unroll
      for (int mf = 0; mf < 4; ++mf)
#pragma unroll
        for (int nf = 0; nf < 4; ++nf)
          acc[mf][nf] = __builtin_amdgcn_mfma_f32_16x16x32_bf16(
              af[ks][mf], bfv[ks][nf], acc[mf][nf], 0, 0, 0);
    __syncthreads();
  }

  const int rbase = bm + wr * 64;
  const int cb64 = nb + wc * 64;
  if (region == 2) {
    const int hkv = cb64 >> 6;
#pragma unroll
    for (int mf = 0; mf < 4; ++mf) {
      const int s0 = rbase + mf * 16 + lq * 4;
#pragma unroll
      for (int nf = 0; nf < 4; ++nf) {
        const int d = (cb64 & 63) + nf * 16 + lr;
        ushort4 st;
        st.x = f2bf(acc[mf][nf][0]); st.y = f2bf(acc[mf][nf][1]);
        st.z = f2bf(acc[mf][nf][2]); st.w = f2bf(acc[mf][nf][3]);
        *(ushort4*)&Vt[(size_t)hkv * 131072 + (size_t)d * 2048 + s0] = st;
      }
    }
  } else {
    u16* outp = region ? Kb : Qb;
    const int ldo = region ? 512 : 2048;
    // Q: 1/8 * log2(e); K: 1.0
    const float post = region ? 1.0f : 0.18033688011112042f;
#pragma unroll
    for (int mf = 0; mf < 4; ++mf)
#pragma unroll
      for (int r = 0; r < 4; ++r) {
        const int s = rbase + mf * 16 + lq * 4 + r;
        const float* cr = cosp + s * 64;
        const float* sr = sinp + s * 64;
#pragma unroll
        for (int nf = 0; nf < 2; ++nf) {
          const int d1 = nf * 16 + lr, d2 = d1 + 32;
          const float x1 = acc[mf][nf][r], x2 = acc[mf][nf + 2][r];
          const float y1 = (x1 * cr[d1] - x2 * sr[d1]) * post;
          const float y2 = (x2 * cr[d2] + x1 * sr[d2]) * post;
          outp[(size_t)s * ldo + cb64 + d1] = f2bf(y1);
          outp[(size_t)s * ldo + cb64 + d2] = f2bf(y2);
        }
      }
  }
}

// ---------------------------------------------------------------------------
// out-proj GEMM (bf16 in, f32 out), 128x128 tile
// ---------------------------------------------------------------------------
__global__ __launch_bounds__(256) void gemm_out(
    const u16* __restrict__ A, const u16* __restrict__ B, float* __restrict__ C,
    int M, int N, int K) {
  __shared__ u16 As[128 * 64];
  __shared__ u16 Bs[128 * 64];
  const int tid = threadIdx.x;
  const int lane = tid & 63, w = tid >> 6;
  const int wr = w >> 1, wc = w & 1;
  const int lr = lane & 15, lq = lane >> 4;
  const int bm = blockIdx.y << 7, bn = blockIdx.x << 7;

  f32x4 acc[4][4] = {};
  const int nK = K >> 6;
  for (int kt = 0; kt < nK; ++kt) {
    const int k0 = kt << 6;
#pragma unroll
    for (int i = 0; i < 4; ++i) {
      const int seg = (i << 2) + w;
      const int idx = (seg << 6) + lane;
      const int r = idx >> 3, c = idx & 7;
      const int cs = (c ^ (r & 7)) << 3;
      gload_lds16(A + (size_t)(bm + r) * K + k0 + cs, (char*)As + seg * 1024);
      gload_lds16(B + (size_t)(bn + r) * K + k0 + cs, (char*)Bs + seg * 1024);
    }
    __syncthreads();
    bf16x8 af[2][4], bfv[2][4];
#pragma unroll
    for (int ks = 0; ks < 2; ++ks) {
#pragma unroll
      for (int f = 0; f < 4; ++f) {
        const int ra = wr * 64 + f * 16 + lr;
        const int ca = (lq + (ks << 2)) ^ (ra & 7);
        af[ks][f] = *(const bf16x8*)&As[((ra << 3) | ca) << 3];
        const int rb = wc * 64 + f * 16 + lr;
        const int cb = (lq + (ks << 2)) ^ (rb & 7);
        bfv[ks][f] = *(const bf16x8*)&Bs[((rb << 3) | cb) << 3];
      }
    }
#pragma unroll
    for (int ks = 0; ks < 2; ++ks)
#pragma unroll
      for (int mf = 0; mf < 4; ++mf)
#pragma unroll
        for (int nf = 0; nf < 4; ++nf)
          acc[mf][nf] = __builtin_amdgcn_mfma_f32_16x16x32_bf16(
              af[ks][mf], bfv[ks][nf], acc[mf][nf], 0, 0, 0);
    __syncthreads();
  }
  const int rbase = bm + wr * 64;
  const int cbase = bn + wc * 64;
#pragma unroll
  for (int mf = 0; mf < 4; ++mf)
#pragma unroll
    for (int r = 0; r < 4; ++r) {
      const int s = rbase + mf * 16 + lq * 4 + r;
#pragma unroll
      for (int nf = 0; nf < 4; ++nf)
        C[(size_t)s * N + cbase + nf * 16 + lr] = acc[mf][nf][r];
    }
}

// ---------------------------------------------------------------------------
// Attention v8: 64-kv tiles staged to LDS (coalesced global_load_lds with
// source-side XOR chunk swizzle; ds_read_b128 fragments with same swizzle),
// double-buffered, prefetch between barriers. K/V tile shared by all 4 waves
// (kills the 64-line-per-load gather that bound v3-v6). No-max exp2 softmax
// (scores Cauchy-Schwarz bounded), split-KV x2, merge = (o0+o1)/(l0+l1).
// ---------------------------------------------------------------------------
__global__ __launch_bounds__(256, 4) void attn_v8(
    const u16* __restrict__ Qb, const u16* __restrict__ Kb,
    const u16* __restrict__ Vt, u16* __restrict__ P0, u16* __restrict__ P1,
    float* __restrict__ lsum) {
  __shared__ u16 Ks[2][4096];   // [buf][64 kv rows x 64 d], 128 B rows, swizzled
  __shared__ u16 Vs[2][4096];   // [buf][64 d rows x 64 kv], 128 B rows, swizzled
  const int hkv = blockIdx.y;
  const int qb = (hkv & 4) ? (63 - (int)blockIdx.x) : (int)blockIdx.x;
  const int chunk = blockIdx.z;
  const int tid = threadIdx.x;
  const int w = tid >> 6, lane = tid & 63;
  const int col = lane & 31, hi = lane >> 5;
  const int g = col >> 3, r = col & 7;
  const int q0w = qb * 32 + w * 8;
  const int qg = q0w + r;
  const int h = hkv * 4 + g;

  const int nt = (qb >> 1) + 1;     // 64-kv tiles for this q block
  const int half = nt >> 1;
  const int t0 = chunk ? half : 0;
  const int t1 = chunk ? nt : half;

  const u16* qp = Qb + (size_t)qg * 2048 + h * 64 + hi * 8;
  uint4 qf[4];
#pragma unroll
  for (int s = 0; s < 4; ++s) qf[s] = *(const uint4*)(qp + 16 * s);

  f32x16 o0 = {}, o1 = {};
  float l_loc = 0.f;

  // stage one 64-kv tile: K (64 rows x 8 chunks) + V (64 d-rows x 8 chunks)
  auto STAGE = [&](int buf, int t) {
    const int kv0 = t << 6;
#pragma unroll
    for (int i = 0; i < 2; ++i) {
      const int cid = i * 256 + tid;           // chunk id 0..511
      const int rr = cid >> 3, cc = cid & 7;
      const int csw = (cc ^ (rr & 7)) << 3;    // pre-swizzled elem offset
      gload_lds16(Kb + (size_t)(kv0 + rr) * 512 + hkv * 64 + csw,
                  (char*)Ks + buf * 8192 + cid * 16);
      gload_lds16(Vt + (size_t)hkv * 131072 + (size_t)rr * 2048 + kv0 + csw,
                  (char*)Vs + buf * 8192 + cid * 16);
    }
  };

  if (t0 < t1) {
    STAGE(0, t0);
    for (int t = t0; t < t1; ++t) {
      const int buf = (t - t0) & 1;
      __syncthreads();                       // cur tile staged; all waves ready
      if (t + 1 < t1) STAGE(buf ^ 1, t + 1); // prefetch overlaps compute
      const char* Kl = (const char*)Ks + buf * 8192;
      const char* Vl = (const char*)Vs + buf * 8192;

      // QK^T: sc0 = kv rows 0..31, sc1 = 32..63 (A=K, B=Q; lane col = q)
      f32x16 sc0 = {}, sc1 = {};
#pragma unroll
      for (int s = 0; s < 4; ++s) {
        const int c = 2 * s + hi;
        const bf16x8 k0 = *(const bf16x8*)(Kl + (((col) << 3) + (c ^ (col & 7))) * 16);
        sc0 = __builtin_amdgcn_mfma_f32_32x32x16_bf16(
            k0, __builtin_bit_cast(bf16x8, qf[s]), sc0, 0, 0, 0);
        const bf16x8 k1 = *(const bf16x8*)(Kl + (((col + 32) << 3) + (c ^ (col & 7))) * 16);
        sc1 = __builtin_amdgcn_mfma_f32_32x32x16_bf16(
            k1, __builtin_bit_cast(bf16x8, qf[s]), sc1, 0, 0, 0);
      }

      if (t == nt - 1) {  // diagonal tile mask
        const int qoff = ((qb & 1) << 5) + w * 8 + r;
#pragma unroll
        for (int i = 0; i < 16; ++i) {
          const int kvr = (i & 3) + 8 * (i >> 2) + 4 * hi;
          if (kvr > qoff) sc0[i] = -1e30f;
          if (kvr + 32 > qoff) sc1[i] = -1e30f;
        }
      }

      // absolute-scale p (no max); sc dies here
      float p0[16], p1[16];
#pragma unroll
      for (int i = 0; i < 16; ++i) { p0[i] = exp2f(sc0[i]); p1[i] = exp2f(sc1[i]); }

      float r0 = 0.f, r1 = 0.f, r2 = 0.f, r3 = 0.f;
#pragma unroll
      for (int i = 0; i < 4; ++i) {
        r0 += p0[4 * i]     + p1[4 * i];
        r1 += p0[4 * i + 1] + p1[4 * i + 1];
        r2 += p0[4 * i + 2] + p1[4 * i + 2];
        r3 += p0[4 * i + 3] + p1[4 * i + 3];
      }
      l_loc += (r0 + r1) + (r2 + r3);

      // pack P to bf16 words
      unsigned W0a[4], W1a[4], W0b[4], W1b[4];
#pragma unroll
      for (int gg = 0; gg < 4; ++gg) {
        W0a[gg] = cvtpk(p0[4 * gg], p0[4 * gg + 1]);
        W1a[gg] = cvtpk(p0[4 * gg + 2], p0[4 * gg + 3]);
        W0b[gg] = cvtpk(p1[4 * gg], p1[4 * gg + 1]);
        W1b[gg] = cvtpk(p1[4 * gg + 2], p1[4 * gg + 3]);
      }

      // PV over 4 kv-16-chunks; V A-frags from LDS (d rows = col, col+32)
#pragma unroll
      for (int s2 = 0; s2 < 4; ++s2) {
        const unsigned* W0 = (s2 & 2) ? W0b : W0a;
        const unsigned* W1 = (s2 & 2) ? W1b : W1a;
        const int G = s2 & 1, ga = 2 * G, gb = 2 * G + 1;
        const unsigned sx0 = hi ? W0[ga] : W0[gb];
        const unsigned sx1 = hi ? W1[ga] : W1[gb];
        const unsigned rx0 = __shfl_xor(sx0, 32, 64);
        const unsigned rx1 = __shfl_xor(sx1, 32, 64);
        uint4 pw;
        pw.x = hi ? rx0 : W0[ga];
        pw.y = hi ? rx1 : W1[ga];
        pw.z = hi ? W0[gb] : rx0;
        pw.w = hi ? W1[gb] : rx1;
        const bf16x8 pf = __builtin_bit_cast(bf16x8, pw);
        const int c = 2 * s2 + hi;
        const bf16x8 v0 = *(const bf16x8*)(Vl + (((col) << 3) + (c ^ (col & 7))) * 16);
        const bf16x8 v1 = *(const bf16x8*)(Vl + (((col + 32) << 3) + (c ^ (col & 7))) * 16);
        o0 = __builtin_amdgcn_mfma_f32_32x32x16_bf16(v0, pf, o0, 0, 0, 0);
        o1 = __builtin_amdgcn_mfma_f32_32x32x16_bf16(v1, pf, o1, 0, 0, 0);
      }
      __syncthreads();                       // all waves done reading buf
    }
  }

  const float l = l_loc + __shfl_xor(l_loc, 32, 64);

  // store unnormalized partials (bf16) + l
  u16* Pc = chunk ? P1 : P0;
  u16* op = Pc + (size_t)qg * 2048 + h * 64;
#pragma unroll
  for (int gg = 0; gg < 4; ++gg) {
    uint2 s0, s1;
    s0.x = cvtpk(o0[4 * gg], o0[4 * gg + 1]);
    s0.y = cvtpk(o0[4 * gg + 2], o0[4 * gg + 3]);
    s1.x = cvtpk(o1[4 * gg], o1[4 * gg + 1]);
    s1.y = cvtpk(o1[4 * gg + 2], o1[4 * gg + 3]);
    *(uint2*)(op + 8 * gg + 4 * hi)      = s0;
    *(uint2*)(op + 8 * gg + 4 * hi + 32) = s1;
  }
  if (hi == 0)
    lsum[(size_t)chunk * 65536 + (size_t)qg * 32 + h] = l;
}

// ---------------------------------------------------------------------------
// merge the two KV-chunk partials -> ctx bf16 (absolute scale: o/(l0+l1))
// ---------------------------------------------------------------------------
__global__ __launch_bounds__(256) void attn_merge(
    const u16* __restrict__ P0, const u16* __restrict__ P1,
    const float* __restrict__ lsum, u16* __restrict__ Cx) {
  const int s = blockIdx.x;
  const int e0 = threadIdx.x * 8;
  const int h = e0 >> 6;
  const float l0 = lsum[(size_t)s * 32 + h];
  const float l1 = lsum[65536 + (size_t)s * 32 + h];
  const float inv = 1.f / (l0 + l1);
  uint4 a = *(const uint4*)(P0 + (size_t)s * 2048 + e0);
  uint4 b = *(const uint4*)(P1 + (size_t)s * 2048 + e0);
  const u16* pa = (const u16*)&a;
  const u16* pb = (const u16*)&b;
  ushort4 oA, oB;
  oA.x = f2bf((bf2f(pa[0]) + bf2f(pb[0])) * inv);
  oA.y = f2bf((bf2f(pa[1]) + bf2f(pb[1])) * inv);
  oA.z = f2bf((bf2f(pa[2]) + bf2f(pb[2])) * inv);
  oA.w = f2bf((bf2f(pa[3]) + bf2f(pb[3])) * inv);
  oB.x = f2bf((bf2f(pa[4]) + bf2f(pb[4])) * inv);
  oB.y = f2bf((bf2f(pa[5]) + bf2f(pb[5])) * inv);
  oB.z = f2bf((bf2f(pa[6]) + bf2f(pb[6])) * inv);
  oB.w = f2bf((bf2f(pa[7]) + bf2f(pb[7])) * inv);
  *(ushort4*)(Cx + (size_t)s * 2048 + e0)     = oA;
  *(ushort4*)(Cx + (size_t)s * 2048 + e0 + 4) = oB;
}

// ---------------------------------------------------------------------------
extern "C" void kernel_launch(void* const* d_in, const int* in_sizes, int n_in,
                              void* d_out, int out_size, void* d_ws, size_t ws_size,
                              hipStream_t stream) {
  const float* X    = (const float*)d_in[0];
  const float* cosp = (const float*)d_in[1];
  const float* sinp = (const float*)d_in[2];
  const float* Wq   = (const float*)d_in[3];
  const float* Wk   = (const float*)d_in[4];
  const float* Wv   = (const float*)d_in[5];
  const float* Wo   = (const float*)d_in[6];

  u16* ws  = (u16*)d_ws;
  u16* Xb  = ws;                         // 2048x2048 (later reused as P0)
  u16* Wqb = ws + 4194304;               // 2048x2048 (later reused as P1)
  u16* Wkb = ws + 8388608;               // 512x2048  (later reused as lsum)
  u16* Wvb = ws + 9437184;               // 512x2048
  u16* Wob = ws + 10485760;              // 2048x2048
  u16* Qb  = ws + 14680064;              // 2048x2048 (rope'd, *log2e/8)
  u16* Kb  = ws + 18874368;              // 2048x512  (rope'd)
  u16* Vt  = ws + 19922944;              // 8x64x2048 (V transposed per head)
  u16* Cx  = ws + 20971520;              // 2048x2048 ctx
  u16* P0  = Xb;
  u16* P1  = Wqb;
  float* lsum = (float*)(ws + 8388608);

  cvt_all<<<3584, 256, 0, stream>>>(X, Wq, Wk, Wv, Wo, Xb, Wqb, Wkb, Wvb, Wob);

  dim3 gqkv(24, 16), ga(64, 8, 2), go(16, 16);
  gemm_qkv<<<gqkv, 256, 0, stream>>>(Xb, Wqb, Wkb, Wvb, Qb, Kb, Vt, cosp, sinp);
  attn_v8<<<ga, 256, 0, stream>>>(Qb, Kb, Vt, P0, P1, lsum);
  attn_merge<<<2048, 256, 0, stream>>>(P0, P1, lsum, Cx);
  gemm_out<<<go, 256, 0, stream>>>(Cx, Wob, (float*)d_out, 2048, 2048, 2048);
}

// Round 9
// 125.970 us; speedup vs baseline: 1.7370x; 1.1565x over previous
//
#include <hip/hip_runtime.h>

typedef unsigned short u16;
typedef __bf16 bf16x8 __attribute__((ext_vector_type(8)));
typedef float f32x4 __attribute__((ext_vector_type(4)));
typedef float f32x16 __attribute__((ext_vector_type(16)));

static __device__ __forceinline__ u16 f2bf(float f) {
  unsigned u = __builtin_bit_cast(unsigned, f);
  u += 0x7fffu + ((u >> 16) & 1u);
  return (u16)(u >> 16);
}
static __device__ __forceinline__ float bf2f(u16 u) {
  return __builtin_bit_cast(float, (unsigned)u << 16);
}
// packed f32x2 -> bf16x2 (single VALU op)
static __device__ __forceinline__ unsigned cvtpk(float lo, float hi) {
  unsigned r;
  asm("v_cvt_pk_bf16_f32 %0, %1, %2" : "=v"(r) : "v"(lo), "v"(hi));
  return r;
}

static __device__ __forceinline__ void gload_lds16(const void* g, void* l) {
  __builtin_amdgcn_global_load_lds((const __attribute__((address_space(1))) unsigned int*)g,
                                   (__attribute__((address_space(3))) unsigned int*)l,
                                   16, 0, 0);
}

// ---------------------------------------------------------------------------
// fp32 -> bf16 conversion for X, Wq, Wk, Wv, Wo (one launch)
// ---------------------------------------------------------------------------
__global__ __launch_bounds__(256) void cvt_all(
    const float* __restrict__ X, const float* __restrict__ Wq, const float* __restrict__ Wk,
    const float* __restrict__ Wv, const float* __restrict__ Wo,
    u16* __restrict__ oX, u16* __restrict__ oWq, u16* __restrict__ oWk,
    u16* __restrict__ oWv, u16* __restrict__ oWo) {
  const int b = blockIdx.x;
  const float* s; u16* d; int lb;
  if (b < 1024)      { s = X;  d = oX;  lb = b; }
  else if (b < 2048) { s = Wq; d = oWq; lb = b - 1024; }
  else if (b < 2304) { s = Wk; d = oWk; lb = b - 2048; }
  else if (b < 2560) { s = Wv; d = oWv; lb = b - 2304; }
  else               { s = Wo; d = oWo; lb = b - 2560; }
  const int base = lb * 4096 + threadIdx.x * 4;
#pragma unroll
  for (int j = 0; j < 4; ++j) {
    const int off = base + j * 1024;
    float4 v = *(const float4*)(s + off);
    ushort4 u;
    u.x = f2bf(v.x); u.y = f2bf(v.y); u.z = f2bf(v.z); u.w = f2bf(v.w);
    *(ushort4*)(d + off) = u;
  }
}

// ---------------------------------------------------------------------------
// Fused QKV GEMM over virtual N=3072: [Wq | Wk | Wv]. BM=64 x BN=128, BK=64.
// 768 blocks (3/CU) for latency hiding. 4 waves (2x2), wave tile 32x64.
// Q epilogue folds 1/sqrt(D)*log2(e); K RoPE; V -> transposed Vt write.
// ---------------------------------------------------------------------------
__global__ __launch_bounds__(256, 4) void gemm_qkv(
    const u16* __restrict__ A, const u16* __restrict__ Bq, const u16* __restrict__ Bk,
    const u16* __restrict__ Bv, u16* __restrict__ Qb, u16* __restrict__ Kb,
    u16* __restrict__ Vt, const float* __restrict__ cosp, const float* __restrict__ sinp) {
  __shared__ u16 As[64 * 64];
  __shared__ u16 Bs[128 * 64];
  const int tid = threadIdx.x;
  const int lane = tid & 63, w = tid >> 6;
  const int wr = w >> 1, wc = w & 1;
  const int lr = lane & 15, lq = lane >> 4;
  const int bm = blockIdx.y << 6;
  const int bn = blockIdx.x << 7;
  const int K = 2048;

  const u16* Bp; int nb, region;
  if (bn < 2048)      { Bp = Bq; nb = bn;        region = 0; }
  else if (bn < 2560) { Bp = Bk; nb = bn - 2048; region = 1; }
  else                { Bp = Bv; nb = bn - 2560; region = 2; }

  f32x4 acc[2][4] = {};

  for (int kt = 0; kt < 32; ++kt) {
    const int k0 = kt << 6;
#pragma unroll
    for (int i = 0; i < 2; ++i) {
      const int cid = (i << 8) + tid;          // A chunks 0..511
      const int r = cid >> 3, c = cid & 7;
      const int cs = (c ^ (r & 7)) << 3;
      gload_lds16(A + (size_t)(bm + r) * K + k0 + cs, (char*)As + cid * 16);
    }
#pragma unroll
    for (int i = 0; i < 4; ++i) {
      const int cid = (i << 8) + tid;          // B chunks 0..1023
      const int r = cid >> 3, c = cid & 7;
      const int cs = (c ^ (r & 7)) << 3;
      gload_lds16(Bp + (size_t)(nb + r) * K + k0 + cs, (char*)Bs + cid * 16);
    }
    __syncthreads();
    bf16x8 af[2][2], bfv[2][4];
#pragma unroll
    for (int ks = 0; ks < 2; ++ks) {
#pragma unroll
      for (int f = 0; f < 2; ++f) {
        const int ra = wr * 32 + f * 16 + lr;
        const int ca = (lq + (ks << 2)) ^ (ra & 7);
        af[ks][f] = *(const bf16x8*)&As[((ra << 3) | ca) << 3];
      }
#pragma unroll
      for (int f = 0; f < 4; ++f) {
        const int rb = wc * 64 + f * 16 + lr;
        const int cb = (lq + (ks << 2)) ^ (rb & 7);
        bfv[ks][f] = *(const bf16x8*)&Bs[((rb << 3) | cb) << 3];
      }
    }
#pragma unroll
    for (int ks = 0; ks < 2; ++ks)
#pragma unroll
      for (int mf = 0; mf < 2; ++mf)
#pragma unroll
        for (int nf = 0; nf < 4; ++nf)
          acc[mf][nf] = __builtin_amdgcn_mfma_f32_16x16x32_bf16(
              af[ks][mf], bfv[ks][nf], acc[mf][nf], 0, 0, 0);
    __syncthreads();
  }

  const int rbase = bm + wr * 32;
  const int cb64 = nb + wc * 64;
  if (region == 2) {
    const int hkv = cb64 >> 6;
#pragma unroll
    for (int mf = 0; mf < 2; ++mf) {
      const int s0 = rbase + mf * 16 + lq * 4;
#pragma unroll
      for (int nf = 0; nf < 4; ++nf) {
        const int d = (cb64 & 63) + nf * 16 + lr;
        ushort4 st;
        st.x = f2bf(acc[mf][nf][0]); st.y = f2bf(acc[mf][nf][1]);
        st.z = f2bf(acc[mf][nf][2]); st.w = f2bf(acc[mf][nf][3]);
        *(ushort4*)&Vt[(size_t)hkv * 131072 + (size_t)d * 2048 + s0] = st;
      }
    }
  } else {
    u16* outp = region ? Kb : Qb;
    const int ldo = region ? 512 : 2048;
    // Q: 1/8 * log2(e); K: 1.0
    const float post = region ? 1.0f : 0.18033688011112042f;
#pragma unroll
    for (int mf = 0; mf < 2; ++mf)
#pragma unroll
      for (int r = 0; r < 4; ++r) {
        const int s = rbase + mf * 16 + lq * 4 + r;
        const float* cr = cosp + s * 64;
        const float* sr = sinp + s * 64;
#pragma unroll
        for (int nf = 0; nf < 2; ++nf) {
          const int d1 = nf * 16 + lr, d2 = d1 + 32;
          const float x1 = acc[mf][nf][r], x2 = acc[mf][nf + 2][r];
          const float y1 = (x1 * cr[d1] - x2 * sr[d1]) * post;
          const float y2 = (x2 * cr[d2] + x1 * sr[d2]) * post;
          outp[(size_t)s * ldo + cb64 + d1] = f2bf(y1);
          outp[(size_t)s * ldo + cb64 + d2] = f2bf(y2);
        }
      }
  }
}

// ---------------------------------------------------------------------------
// out-proj GEMM (bf16 in, f32 out), BM=64 x BN=128 (512 blocks = 2/CU)
// ---------------------------------------------------------------------------
__global__ __launch_bounds__(256, 4) void gemm_out(
    const u16* __restrict__ A, const u16* __restrict__ B, float* __restrict__ C,
    int M, int N, int K) {
  __shared__ u16 As[64 * 64];
  __shared__ u16 Bs[128 * 64];
  const int tid = threadIdx.x;
  const int lane = tid & 63, w = tid >> 6;
  const int wr = w >> 1, wc = w & 1;
  const int lr = lane & 15, lq = lane >> 4;
  const int bm = blockIdx.y << 6, bn = blockIdx.x << 7;

  f32x4 acc[2][4] = {};
  const int nK = K >> 6;
  for (int kt = 0; kt < nK; ++kt) {
    const int k0 = kt << 6;
#pragma unroll
    for (int i = 0; i < 2; ++i) {
      const int cid = (i << 8) + tid;
      const int r = cid >> 3, c = cid & 7;
      const int cs = (c ^ (r & 7)) << 3;
      gload_lds16(A + (size_t)(bm + r) * K + k0 + cs, (char*)As + cid * 16);
    }
#pragma unroll
    for (int i = 0; i < 4; ++i) {
      const int cid = (i << 8) + tid;
      const int r = cid >> 3, c = cid & 7;
      const int cs = (c ^ (r & 7)) << 3;
      gload_lds16(B + (size_t)(bn + r) * K + k0 + cs, (char*)Bs + cid * 16);
    }
    __syncthreads();
    bf16x8 af[2][2], bfv[2][4];
#pragma unroll
    for (int ks = 0; ks < 2; ++ks) {
#pragma unroll
      for (int f = 0; f < 2; ++f) {
        const int ra = wr * 32 + f * 16 + lr;
        const int ca = (lq + (ks << 2)) ^ (ra & 7);
        af[ks][f] = *(const bf16x8*)&As[((ra << 3) | ca) << 3];
      }
#pragma unroll
      for (int f = 0; f < 4; ++f) {
        const int rb = wc * 64 + f * 16 + lr;
        const int cb = (lq + (ks << 2)) ^ (rb & 7);
        bfv[ks][f] = *(const bf16x8*)&Bs[((rb << 3) | cb) << 3];
      }
    }
#pragma unroll
    for (int ks = 0; ks < 2; ++ks)
#pragma unroll
      for (int mf = 0; mf < 2; ++mf)
#pragma unroll
        for (int nf = 0; nf < 4; ++nf)
          acc[mf][nf] = __builtin_amdgcn_mfma_f32_16x16x32_bf16(
              af[ks][mf], bfv[ks][nf], acc[mf][nf], 0, 0, 0);
    __syncthreads();
  }
  const int rbase = bm + wr * 32;
  const int cbase = bn + wc * 64;
#pragma unroll
  for (int mf = 0; mf < 2; ++mf)
#pragma unroll
    for (int r = 0; r < 4; ++r) {
      const int s = rbase + mf * 16 + lq * 4 + r;
#pragma unroll
      for (int nf = 0; nf < 4; ++nf)
        C[(size_t)s * N + cbase + nf * 16 + lr] = acc[mf][nf][r];
    }
}

// ---------------------------------------------------------------------------
// Attention v8: 64-kv tiles staged to LDS (coalesced global_load_lds with
// source-side XOR chunk swizzle; ds_read_b128 fragments with same swizzle),
// double-buffered, prefetch between barriers. No-max exp2 softmax, split-KV
// x2, merge = (o0+o1)/(l0+l1).
// ---------------------------------------------------------------------------
__global__ __launch_bounds__(256, 4) void attn_v8(
    const u16* __restrict__ Qb, const u16* __restrict__ Kb,
    const u16* __restrict__ Vt, u16* __restrict__ P0, u16* __restrict__ P1,
    float* __restrict__ lsum) {
  __shared__ u16 Ks[2][4096];   // [buf][64 kv rows x 64 d], 128 B rows, swizzled
  __shared__ u16 Vs[2][4096];   // [buf][64 d rows x 64 kv], 128 B rows, swizzled
  const int hkv = blockIdx.y;
  const int qb = (hkv & 4) ? (63 - (int)blockIdx.x) : (int)blockIdx.x;
  const int chunk = blockIdx.z;
  const int tid = threadIdx.x;
  const int w = tid >> 6, lane = tid & 63;
  const int col = lane & 31, hi = lane >> 5;
  const int g = col >> 3, r = col & 7;
  const int q0w = qb * 32 + w * 8;
  const int qg = q0w + r;
  const int h = hkv * 4 + g;

  const int nt = (qb >> 1) + 1;     // 64-kv tiles for this q block
  const int half = nt >> 1;
  const int t0 = chunk ? half : 0;
  const int t1 = chunk ? nt : half;

  const u16* qp = Qb + (size_t)qg * 2048 + h * 64 + hi * 8;
  uint4 qf[4];
#pragma unroll
  for (int s = 0; s < 4; ++s) qf[s] = *(const uint4*)(qp + 16 * s);

  f32x16 o0 = {}, o1 = {};
  float l_loc = 0.f;

  // stage one 64-kv tile: K (64 rows x 8 chunks) + V (64 d-rows x 8 chunks)
  auto STAGE = [&](int buf, int t) {
    const int kv0 = t << 6;
#pragma unroll
    for (int i = 0; i < 2; ++i) {
      const int cid = i * 256 + tid;           // chunk id 0..511
      const int rr = cid >> 3, cc = cid & 7;
      const int csw = (cc ^ (rr & 7)) << 3;    // pre-swizzled elem offset
      gload_lds16(Kb + (size_t)(kv0 + rr) * 512 + hkv * 64 + csw,
                  (char*)Ks + buf * 8192 + cid * 16);
      gload_lds16(Vt + (size_t)hkv * 131072 + (size_t)rr * 2048 + kv0 + csw,
                  (char*)Vs + buf * 8192 + cid * 16);
    }
  };

  if (t0 < t1) {
    STAGE(0, t0);
    for (int t = t0; t < t1; ++t) {
      const int buf = (t - t0) & 1;
      __syncthreads();                       // cur tile staged; all waves ready
      if (t + 1 < t1) STAGE(buf ^ 1, t + 1); // prefetch overlaps compute
      const char* Kl = (const char*)Ks + buf * 8192;
      const char* Vl = (const char*)Vs + buf * 8192;

      // QK^T: sc0 = kv rows 0..31, sc1 = 32..63 (A=K, B=Q; lane col = q)
      f32x16 sc0 = {}, sc1 = {};
#pragma unroll
      for (int s = 0; s < 4; ++s) {
        const int c = 2 * s + hi;
        const bf16x8 k0 = *(const bf16x8*)(Kl + (((col) << 3) + (c ^ (col & 7))) * 16);
        sc0 = __builtin_amdgcn_mfma_f32_32x32x16_bf16(
            k0, __builtin_bit_cast(bf16x8, qf[s]), sc0, 0, 0, 0);
        const bf16x8 k1 = *(const bf16x8*)(Kl + (((col + 32) << 3) + (c ^ (col & 7))) * 16);
        sc1 = __builtin_amdgcn_mfma_f32_32x32x16_bf16(
            k1, __builtin_bit_cast(bf16x8, qf[s]), sc1, 0, 0, 0);
      }

      if (t == nt - 1) {  // diagonal tile mask
        const int qoff = ((qb & 1) << 5) + w * 8 + r;
#pragma unroll
        for (int i = 0; i < 16; ++i) {
          const int kvr = (i & 3) + 8 * (i >> 2) + 4 * hi;
          if (kvr > qoff) sc0[i] = -1e30f;
          if (kvr + 32 > qoff) sc1[i] = -1e30f;
        }
      }

      // absolute-scale p (no max); sc dies here
      float p0[16], p1[16];
#pragma unroll
      for (int i = 0; i < 16; ++i) { p0[i] = exp2f(sc0[i]); p1[i] = exp2f(sc1[i]); }

      float r0 = 0.f, r1 = 0.f, r2 = 0.f, r3 = 0.f;
#pragma unroll
      for (int i = 0; i < 4; ++i) {
        r0 += p0[4 * i]     + p1[4 * i];
        r1 += p0[4 * i + 1] + p1[4 * i + 1];
        r2 += p0[4 * i + 2] + p1[4 * i + 2];
        r3 += p0[4 * i + 3] + p1[4 * i + 3];
      }
      l_loc += (r0 + r1) + (r2 + r3);

      // pack P to bf16 words
      unsigned W0a[4], W1a[4], W0b[4], W1b[4];
#pragma unroll
      for (int gg = 0; gg < 4; ++gg) {
        W0a[gg] = cvtpk(p0[4 * gg], p0[4 * gg + 1]);
        W1a[gg] = cvtpk(p0[4 * gg + 2], p0[4 * gg + 3]);
        W0b[gg] = cvtpk(p1[4 * gg], p1[4 * gg + 1]);
        W1b[gg] = cvtpk(p1[4 * gg + 2], p1[4 * gg + 3]);
      }

      // PV over 4 kv-16-chunks; V A-frags from LDS (d rows = col, col+32)
#pragma unroll
      for (int s2 = 0; s2 < 4; ++s2) {
        const unsigned* W0 = (s2 & 2) ? W0b : W0a;
        const unsigned* W1 = (s2 & 2) ? W1b : W1a;
        const int G = s2 & 1, ga = 2 * G, gb = 2 * G + 1;
        const unsigned sx0 = hi ? W0[ga] : W0[gb];
        const unsigned sx1 = hi ? W1[ga] : W1[gb];
        const unsigned rx0 = __shfl_xor(sx0, 32, 64);
        const unsigned rx1 = __shfl_xor(sx1, 32, 64);
        uint4 pw;
        pw.x = hi ? rx0 : W0[ga];
        pw.y = hi ? rx1 : W1[ga];
        pw.z = hi ? W0[gb] : rx0;
        pw.w = hi ? W1[gb] : rx1;
        const bf16x8 pf = __builtin_bit_cast(bf16x8, pw);
        const int c = 2 * s2 + hi;
        const bf16x8 v0 = *(const bf16x8*)(Vl + (((col) << 3) + (c ^ (col & 7))) * 16);
        const bf16x8 v1 = *(const bf16x8*)(Vl + (((col + 32) << 3) + (c ^ (col & 7))) * 16);
        o0 = __builtin_amdgcn_mfma_f32_32x32x16_bf16(v0, pf, o0, 0, 0, 0);
        o1 = __builtin_amdgcn_mfma_f32_32x32x16_bf16(v1, pf, o1, 0, 0, 0);
      }
      __syncthreads();                       // all waves done reading buf
    }
  }

  const float l = l_loc + __shfl_xor(l_loc, 32, 64);

  // store unnormalized partials (bf16) + l
  u16* Pc = chunk ? P1 : P0;
  u16* op = Pc + (size_t)qg * 2048 + h * 64;
#pragma unroll
  for (int gg = 0; gg < 4; ++gg) {
    uint2 s0, s1;
    s0.x = cvtpk(o0[4 * gg], o0[4 * gg + 1]);
    s0.y = cvtpk(o0[4 * gg + 2], o0[4 * gg + 3]);
    s1.x = cvtpk(o1[4 * gg], o1[4 * gg + 1]);
    s1.y = cvtpk(o1[4 * gg + 2], o1[4 * gg + 3]);
    *(uint2*)(op + 8 * gg + 4 * hi)      = s0;
    *(uint2*)(op + 8 * gg + 4 * hi + 32) = s1;
  }
  if (hi == 0)
    lsum[(size_t)chunk * 65536 + (size_t)qg * 32 + h] = l;
}

// ---------------------------------------------------------------------------
// merge the two KV-chunk partials -> ctx bf16 (absolute scale: o/(l0+l1))
// ---------------------------------------------------------------------------
__global__ __launch_bounds__(256) void attn_merge(
    const u16* __restrict__ P0, const u16* __restrict__ P1,
    const float* __restrict__ lsum, u16* __restrict__ Cx) {
  const int s = blockIdx.x;
  const int e0 = threadIdx.x * 8;
  const int h = e0 >> 6;
  const float l0 = lsum[(size_t)s * 32 + h];
  const float l1 = lsum[65536 + (size_t)s * 32 + h];
  const float inv = 1.f / (l0 + l1);
  uint4 a = *(const uint4*)(P0 + (size_t)s * 2048 + e0);
  uint4 b = *(const uint4*)(P1 + (size_t)s * 2048 + e0);
  const u16* pa = (const u16*)&a;
  const u16* pb = (const u16*)&b;
  ushort4 oA, oB;
  oA.x = f2bf((bf2f(pa[0]) + bf2f(pb[0])) * inv);
  oA.y = f2bf((bf2f(pa[1]) + bf2f(pb[1])) * inv);
  oA.z = f2bf((bf2f(pa[2]) + bf2f(pb[2])) * inv);
  oA.w = f2bf((bf2f(pa[3]) + bf2f(pb[3])) * inv);
  oB.x = f2bf((bf2f(pa[4]) + bf2f(pb[4])) * inv);
  oB.y = f2bf((bf2f(pa[5]) + bf2f(pb[5])) * inv);
  oB.z = f2bf((bf2f(pa[6]) + bf2f(pb[6])) * inv);
  oB.w = f2bf((bf2f(pa[7]) + bf2f(pb[7])) * inv);
  *(ushort4*)(Cx + (size_t)s * 2048 + e0)     = oA;
  *(ushort4*)(Cx + (size_t)s * 2048 + e0 + 4) = oB;
}

// ---------------------------------------------------------------------------
extern "C" void kernel_launch(void* const* d_in, const int* in_sizes, int n_in,
                              void* d_out, int out_size, void* d_ws, size_t ws_size,
                              hipStream_t stream) {
  const float* X    = (const float*)d_in[0];
  const float* cosp = (const float*)d_in[1];
  const float* sinp = (const float*)d_in[2];
  const float* Wq   = (const float*)d_in[3];
  const float* Wk   = (const float*)d_in[4];
  const float* Wv   = (const float*)d_in[5];
  const float* Wo   = (const float*)d_in[6];

  u16* ws  = (u16*)d_ws;
  u16* Xb  = ws;                         // 2048x2048 (later reused as P0)
  u16* Wqb = ws + 4194304;               // 2048x2048 (later reused as P1)
  u16* Wkb = ws + 8388608;               // 512x2048  (later reused as lsum)
  u16* Wvb = ws + 9437184;               // 512x2048
  u16* Wob = ws + 10485760;              // 2048x2048
  u16* Qb  = ws + 14680064;              // 2048x2048 (rope'd, *log2e/8)
  u16* Kb  = ws + 18874368;              // 2048x512  (rope'd)
  u16* Vt  = ws + 19922944;              // 8x64x2048 (V transposed per head)
  u16* Cx  = ws + 20971520;              // 2048x2048 ctx
  u16* P0  = Xb;
  u16* P1  = Wqb;
  float* lsum = (float*)(ws + 8388608);

  cvt_all<<<3584, 256, 0, stream>>>(X, Wq, Wk, Wv, Wo, Xb, Wqb, Wkb, Wvb, Wob);

  dim3 gqkv(24, 32), ga(64, 8, 2), go(16, 32);
  gemm_qkv<<<gqkv, 256, 0, stream>>>(Xb, Wqb, Wkb, Wvb, Qb, Kb, Vt, cosp, sinp);
  attn_v8<<<ga, 256, 0, stream>>>(Qb, Kb, Vt, P0, P1, lsum);
  attn_merge<<<2048, 256, 0, stream>>>(P0, P1, lsum, Cx);
  gemm_out<<<go, 256, 0, stream>>>(Cx, Wob, (float*)d_out, 2048, 2048, 2048);
}

// Round 10
// 124.352 us; speedup vs baseline: 1.7596x; 1.0130x over previous
//
#include <hip/hip_runtime.h>

typedef unsigned short u16;
typedef __bf16 bf16x8 __attribute__((ext_vector_type(8)));
typedef float f32x4 __attribute__((ext_vector_type(4)));
typedef float f32x16 __attribute__((ext_vector_type(16)));

static __device__ __forceinline__ u16 f2bf(float f) {
  unsigned u = __builtin_bit_cast(unsigned, f);
  u += 0x7fffu + ((u >> 16) & 1u);
  return (u16)(u >> 16);
}
static __device__ __forceinline__ float bf2f(u16 u) {
  return __builtin_bit_cast(float, (unsigned)u << 16);
}
// packed f32x2 -> bf16x2 (single VALU op)
static __device__ __forceinline__ unsigned cvtpk(float lo, float hi) {
  unsigned r;
  asm("v_cvt_pk_bf16_f32 %0, %1, %2" : "=v"(r) : "v"(lo), "v"(hi));
  return r;
}

static __device__ __forceinline__ void gload_lds16(const void* g, void* l) {
  __builtin_amdgcn_global_load_lds((const __attribute__((address_space(1))) unsigned int*)g,
                                   (__attribute__((address_space(3))) unsigned int*)l,
                                   16, 0, 0);
}

// ---------------------------------------------------------------------------
// fp32 -> bf16 conversion for X, Wq, Wk, Wv, Wo (one launch)
// ---------------------------------------------------------------------------
__global__ __launch_bounds__(256) void cvt_all(
    const float* __restrict__ X, const float* __restrict__ Wq, const float* __restrict__ Wk,
    const float* __restrict__ Wv, const float* __restrict__ Wo,
    u16* __restrict__ oX, u16* __restrict__ oWq, u16* __restrict__ oWk,
    u16* __restrict__ oWv, u16* __restrict__ oWo) {
  const int b = blockIdx.x;
  const float* s; u16* d; int lb;
  if (b < 1024)      { s = X;  d = oX;  lb = b; }
  else if (b < 2048) { s = Wq; d = oWq; lb = b - 1024; }
  else if (b < 2304) { s = Wk; d = oWk; lb = b - 2048; }
  else if (b < 2560) { s = Wv; d = oWv; lb = b - 2304; }
  else               { s = Wo; d = oWo; lb = b - 2560; }
  const int base = lb * 4096 + threadIdx.x * 4;
#pragma unroll
  for (int j = 0; j < 4; ++j) {
    const int off = base + j * 1024;
    float4 v = *(const float4*)(s + off);
    ushort4 u;
    u.x = f2bf(v.x); u.y = f2bf(v.y); u.z = f2bf(v.z); u.w = f2bf(v.w);
    *(ushort4*)(d + off) = u;
  }
}

// ---------------------------------------------------------------------------
// Fused QKV GEMM over virtual N=3072: [Wq | Wk | Wv]. BM=64 x BN=128, BK=64.
// 768 blocks (3/CU). Q epilogue folds 1/sqrt(D)*log2(e); K RoPE; V -> Vt.
// ---------------------------------------------------------------------------
__global__ __launch_bounds__(256, 4) void gemm_qkv(
    const u16* __restrict__ A, const u16* __restrict__ Bq, const u16* __restrict__ Bk,
    const u16* __restrict__ Bv, u16* __restrict__ Qb, u16* __restrict__ Kb,
    u16* __restrict__ Vt, const float* __restrict__ cosp, const float* __restrict__ sinp) {
  __shared__ u16 As[64 * 64];
  __shared__ u16 Bs[128 * 64];
  const int tid = threadIdx.x;
  const int lane = tid & 63, w = tid >> 6;
  const int wr = w >> 1, wc = w & 1;
  const int lr = lane & 15, lq = lane >> 4;
  const int bm = blockIdx.y << 6;
  const int bn = blockIdx.x << 7;
  const int K = 2048;

  const u16* Bp; int nb, region;
  if (bn < 2048)      { Bp = Bq; nb = bn;        region = 0; }
  else if (bn < 2560) { Bp = Bk; nb = bn - 2048; region = 1; }
  else                { Bp = Bv; nb = bn - 2560; region = 2; }

  f32x4 acc[2][4] = {};

  for (int kt = 0; kt < 32; ++kt) {
    const int k0 = kt << 6;
#pragma unroll
    for (int i = 0; i < 2; ++i) {
      const int cid = (i << 8) + tid;          // A chunks 0..511
      const int r = cid >> 3, c = cid & 7;
      const int cs = (c ^ (r & 7)) << 3;
      gload_lds16(A + (size_t)(bm + r) * K + k0 + cs, (char*)As + cid * 16);
    }
#pragma unroll
    for (int i = 0; i < 4; ++i) {
      const int cid = (i << 8) + tid;          // B chunks 0..1023
      const int r = cid >> 3, c = cid & 7;
      const int cs = (c ^ (r & 7)) << 3;
      gload_lds16(Bp + (size_t)(nb + r) * K + k0 + cs, (char*)Bs + cid * 16);
    }
    __syncthreads();
    bf16x8 af[2][2], bfv[2][4];
#pragma unroll
    for (int ks = 0; ks < 2; ++ks) {
#pragma unroll
      for (int f = 0; f < 2; ++f) {
        const int ra = wr * 32 + f * 16 + lr;
        const int ca = (lq + (ks << 2)) ^ (ra & 7);
        af[ks][f] = *(const bf16x8*)&As[((ra << 3) | ca) << 3];
      }
#pragma unroll
      for (int f = 0; f < 4; ++f) {
        const int rb = wc * 64 + f * 16 + lr;
        const int cb = (lq + (ks << 2)) ^ (rb & 7);
        bfv[ks][f] = *(const bf16x8*)&Bs[((rb << 3) | cb) << 3];
      }
    }
#pragma unroll
    for (int ks = 0; ks < 2; ++ks)
#pragma unroll
      for (int mf = 0; mf < 2; ++mf)
#pragma unroll
        for (int nf = 0; nf < 4; ++nf)
          acc[mf][nf] = __builtin_amdgcn_mfma_f32_16x16x32_bf16(
              af[ks][mf], bfv[ks][nf], acc[mf][nf], 0, 0, 0);
    __syncthreads();
  }

  const int rbase = bm + wr * 32;
  const int cb64 = nb + wc * 64;
  if (region == 2) {
    const int hkv = cb64 >> 6;
#pragma unroll
    for (int mf = 0; mf < 2; ++mf) {
      const int s0 = rbase + mf * 16 + lq * 4;
#pragma unroll
      for (int nf = 0; nf < 4; ++nf) {
        const int d = (cb64 & 63) + nf * 16 + lr;
        ushort4 st;
        st.x = f2bf(acc[mf][nf][0]); st.y = f2bf(acc[mf][nf][1]);
        st.z = f2bf(acc[mf][nf][2]); st.w = f2bf(acc[mf][nf][3]);
        *(ushort4*)&Vt[(size_t)hkv * 131072 + (size_t)d * 2048 + s0] = st;
      }
    }
  } else {
    u16* outp = region ? Kb : Qb;
    const int ldo = region ? 512 : 2048;
    // Q: 1/8 * log2(e); K: 1.0
    const float post = region ? 1.0f : 0.18033688011112042f;
#pragma unroll
    for (int mf = 0; mf < 2; ++mf)
#pragma unroll
      for (int r = 0; r < 4; ++r) {
        const int s = rbase + mf * 16 + lq * 4 + r;
        const float* cr = cosp + s * 64;
        const float* sr = sinp + s * 64;
#pragma unroll
        for (int nf = 0; nf < 2; ++nf) {
          const int d1 = nf * 16 + lr, d2 = d1 + 32;
          const float x1 = acc[mf][nf][r], x2 = acc[mf][nf + 2][r];
          const float y1 = (x1 * cr[d1] - x2 * sr[d1]) * post;
          const float y2 = (x2 * cr[d2] + x1 * sr[d2]) * post;
          outp[(size_t)s * ldo + cb64 + d1] = f2bf(y1);
          outp[(size_t)s * ldo + cb64 + d2] = f2bf(y2);
        }
      }
  }
}

// ---------------------------------------------------------------------------
// out-proj GEMM (bf16 in, f32 out), BM=64 x BN=128 (512 blocks = 2/CU)
// ---------------------------------------------------------------------------
__global__ __launch_bounds__(256, 4) void gemm_out(
    const u16* __restrict__ A, const u16* __restrict__ B, float* __restrict__ C,
    int M, int N, int K) {
  __shared__ u16 As[64 * 64];
  __shared__ u16 Bs[128 * 64];
  const int tid = threadIdx.x;
  const int lane = tid & 63, w = tid >> 6;
  const int wr = w >> 1, wc = w & 1;
  const int lr = lane & 15, lq = lane >> 4;
  const int bm = blockIdx.y << 6, bn = blockIdx.x << 7;

  f32x4 acc[2][4] = {};
  const int nK = K >> 6;
  for (int kt = 0; kt < nK; ++kt) {
    const int k0 = kt << 6;
#pragma unroll
    for (int i = 0; i < 2; ++i) {
      const int cid = (i << 8) + tid;
      const int r = cid >> 3, c = cid & 7;
      const int cs = (c ^ (r & 7)) << 3;
      gload_lds16(A + (size_t)(bm + r) * K + k0 + cs, (char*)As + cid * 16);
    }
#pragma unroll
    for (int i = 0; i < 4; ++i) {
      const int cid = (i << 8) + tid;
      const int r = cid >> 3, c = cid & 7;
      const int cs = (c ^ (r & 7)) << 3;
      gload_lds16(B + (size_t)(bn + r) * K + k0 + cs, (char*)Bs + cid * 16);
    }
    __syncthreads();
    bf16x8 af[2][2], bfv[2][4];
#pragma unroll
    for (int ks = 0; ks < 2; ++ks) {
#pragma unroll
      for (int f = 0; f < 2; ++f) {
        const int ra = wr * 32 + f * 16 + lr;
        const int ca = (lq + (ks << 2)) ^ (ra & 7);
        af[ks][f] = *(const bf16x8*)&As[((ra << 3) | ca) << 3];
      }
#pragma unroll
      for (int f = 0; f < 4; ++f) {
        const int rb = wc * 64 + f * 16 + lr;
        const int cb = (lq + (ks << 2)) ^ (rb & 7);
        bfv[ks][f] = *(const bf16x8*)&Bs[((rb << 3) | cb) << 3];
      }
    }
#pragma unroll
    for (int ks = 0; ks < 2; ++ks)
#pragma unroll
      for (int mf = 0; mf < 2; ++mf)
#pragma unroll
        for (int nf = 0; nf < 4; ++nf)
          acc[mf][nf] = __builtin_amdgcn_mfma_f32_16x16x32_bf16(
              af[ks][mf], bfv[ks][nf], acc[mf][nf], 0, 0, 0);
    __syncthreads();
  }
  const int rbase = bm + wr * 32;
  const int cbase = bn + wc * 64;
#pragma unroll
  for (int mf = 0; mf < 2; ++mf)
#pragma unroll
    for (int r = 0; r < 4; ++r) {
      const int s = rbase + mf * 16 + lq * 4 + r;
#pragma unroll
      for (int nf = 0; nf < 4; ++nf)
        C[(size_t)s * N + cbase + nf * 16 + lr] = acc[mf][nf][r];
    }
}

// ---------------------------------------------------------------------------
// Attention v9: paired q-blocks for exact load balance. Pair (qb=j, 63-j) has
// a CONSTANT 33-tile causal stream; block = 4 waves processes both members in
// two phases, taking stream slots s % 3 == chunk (grid.z=3) -> every block
// does exactly 11 64-KV tiles. LDS-staged K/V (swizzled gload_lds, dbuf),
// no-max exp2 softmax, 3-way partial merge (o-sums share absolute scale).
// ---------------------------------------------------------------------------
__global__ __launch_bounds__(256, 4) void attn_v9(
    const u16* __restrict__ Qb, const u16* __restrict__ Kb,
    const u16* __restrict__ Vt, u16* __restrict__ P0, u16* __restrict__ P1,
    u16* __restrict__ P2, float* __restrict__ lsum) {
  __shared__ u16 Ks[2][4096];   // [buf][64 kv rows x 64 d], swizzled chunks
  __shared__ u16 Vs[2][4096];   // [buf][64 d rows x 64 kv], swizzled chunks
  const int jp = blockIdx.x;     // pair index 0..31
  const int hkv = blockIdx.y;
  const int ck = blockIdx.z;     // chunk 0..2
  const int tid = threadIdx.x;
  const int w = tid >> 6, lane = tid & 63;
  const int col = lane & 31, hi = lane >> 5;
  const int g = col >> 3, r = col & 7;
  const int h = hkv * 4 + g;

  u16* Pc = (ck == 0) ? P0 : (ck == 1) ? P1 : P2;

  auto STAGE = [&](int buf, int t) {
    const int kv0 = t << 6;
#pragma unroll
    for (int i = 0; i < 2; ++i) {
      const int cid = i * 256 + tid;           // chunk id 0..511
      const int rr = cid >> 3, cc = cid & 7;
      const int csw = (cc ^ (rr & 7)) << 3;    // pre-swizzled elem offset
      gload_lds16(Kb + (size_t)(kv0 + rr) * 512 + hkv * 64 + csw,
                  (char*)Ks + buf * 8192 + cid * 16);
      gload_lds16(Vt + (size_t)hkv * 131072 + (size_t)rr * 2048 + kv0 + csw,
                  (char*)Vs + buf * 8192 + cid * 16);
    }
  };

  int sbase = 0;
#pragma unroll 1
  for (int phase = 0; phase < 2; ++phase) {
    const int qb = phase ? (63 - jp) : jp;
    const int nt = (qb >> 1) + 1;              // 64-KV tiles for this qb
    const int q0w = qb * 32 + w * 8;
    const int qg = q0w + r;

    const u16* qp = Qb + (size_t)qg * 2048 + h * 64 + hi * 8;
    uint4 qf[4];
#pragma unroll
    for (int s = 0; s < 4; ++s) qf[s] = *(const uint4*)(qp + 16 * s);

    f32x16 o0 = {}, o1 = {};
    float l_loc = 0.f;

    int tf = ck - (sbase % 3); if (tf < 0) tf += 3;  // first tile of this chunk
    if (tf < nt) {
      STAGE(0, tf);
      int i = 0;
      for (int t = tf; t < nt; t += 3, ++i) {
        const int buf = i & 1;
        __syncthreads();                       // cur tile staged
        if (t + 3 < nt) STAGE(buf ^ 1, t + 3); // prefetch overlaps compute
        const char* Kl = (const char*)Ks + buf * 8192;
        const char* Vl = (const char*)Vs + buf * 8192;

        // QK^T: sc0 = kv rows 0..31, sc1 = 32..63 (A=K, B=Q; lane col = q)
        f32x16 sc0 = {}, sc1 = {};
#pragma unroll
        for (int s = 0; s < 4; ++s) {
          const int c = 2 * s + hi;
          const bf16x8 k0 = *(const bf16x8*)(Kl + (((col) << 3) + (c ^ (col & 7))) * 16);
          sc0 = __builtin_amdgcn_mfma_f32_32x32x16_bf16(
              k0, __builtin_bit_cast(bf16x8, qf[s]), sc0, 0, 0, 0);
          const bf16x8 k1 = *(const bf16x8*)(Kl + (((col + 32) << 3) + (c ^ (col & 7))) * 16);
          sc1 = __builtin_amdgcn_mfma_f32_32x32x16_bf16(
              k1, __builtin_bit_cast(bf16x8, qf[s]), sc1, 0, 0, 0);
        }

        if (t == nt - 1) {  // diagonal tile mask
          const int qoff = ((qb & 1) << 5) + w * 8 + r;
#pragma unroll
          for (int i2 = 0; i2 < 16; ++i2) {
            const int kvr = (i2 & 3) + 8 * (i2 >> 2) + 4 * hi;
            if (kvr > qoff) sc0[i2] = -1e30f;
            if (kvr + 32 > qoff) sc1[i2] = -1e30f;
          }
        }

        // absolute-scale p (no max); sc dies here
        float p0[16], p1[16];
#pragma unroll
        for (int i2 = 0; i2 < 16; ++i2) { p0[i2] = exp2f(sc0[i2]); p1[i2] = exp2f(sc1[i2]); }

        float r0 = 0.f, r1 = 0.f, r2 = 0.f, r3 = 0.f;
#pragma unroll
        for (int i2 = 0; i2 < 4; ++i2) {
          r0 += p0[4 * i2]     + p1[4 * i2];
          r1 += p0[4 * i2 + 1] + p1[4 * i2 + 1];
          r2 += p0[4 * i2 + 2] + p1[4 * i2 + 2];
          r3 += p0[4 * i2 + 3] + p1[4 * i2 + 3];
        }
        l_loc += (r0 + r1) + (r2 + r3);

        // pack P to bf16 words
        unsigned W0a[4], W1a[4], W0b[4], W1b[4];
#pragma unroll
        for (int gg = 0; gg < 4; ++gg) {
          W0a[gg] = cvtpk(p0[4 * gg], p0[4 * gg + 1]);
          W1a[gg] = cvtpk(p0[4 * gg + 2], p0[4 * gg + 3]);
          W0b[gg] = cvtpk(p1[4 * gg], p1[4 * gg + 1]);
          W1b[gg] = cvtpk(p1[4 * gg + 2], p1[4 * gg + 3]);
        }

        // PV over 4 kv-16-chunks; V A-frags from LDS (d rows = col, col+32)
#pragma unroll
        for (int s2 = 0; s2 < 4; ++s2) {
          const unsigned* W0 = (s2 & 2) ? W0b : W0a;
          const unsigned* W1 = (s2 & 2) ? W1b : W1a;
          const int G = s2 & 1, ga = 2 * G, gb = 2 * G + 1;
          const unsigned sx0 = hi ? W0[ga] : W0[gb];
          const unsigned sx1 = hi ? W1[ga] : W1[gb];
          const unsigned rx0 = __shfl_xor(sx0, 32, 64);
          const unsigned rx1 = __shfl_xor(sx1, 32, 64);
          uint4 pw;
          pw.x = hi ? rx0 : W0[ga];
          pw.y = hi ? rx1 : W1[ga];
          pw.z = hi ? W0[gb] : rx0;
          pw.w = hi ? W1[gb] : rx1;
          const bf16x8 pf = __builtin_bit_cast(bf16x8, pw);
          const int c = 2 * s2 + hi;
          const bf16x8 v0 = *(const bf16x8*)(Vl + (((col) << 3) + (c ^ (col & 7))) * 16);
          const bf16x8 v1 = *(const bf16x8*)(Vl + (((col + 32) << 3) + (c ^ (col & 7))) * 16);
          o0 = __builtin_amdgcn_mfma_f32_32x32x16_bf16(v0, pf, o0, 0, 0, 0);
          o1 = __builtin_amdgcn_mfma_f32_32x32x16_bf16(v1, pf, o1, 0, 0, 0);
        }
        __syncthreads();                       // all waves done reading buf
      }
    }

    const float l = l_loc + __shfl_xor(l_loc, 32, 64);

    // store this phase's partials (zeros if chunk had no tiles here)
    u16* op = Pc + (size_t)qg * 2048 + h * 64;
#pragma unroll
    for (int gg = 0; gg < 4; ++gg) {
      uint2 s0, s1;
      s0.x = cvtpk(o0[4 * gg], o0[4 * gg + 1]);
      s0.y = cvtpk(o0[4 * gg + 2], o0[4 * gg + 3]);
      s1.x = cvtpk(o1[4 * gg], o1[4 * gg + 1]);
      s1.y = cvtpk(o1[4 * gg + 2], o1[4 * gg + 3]);
      *(uint2*)(op + 8 * gg + 4 * hi)      = s0;
      *(uint2*)(op + 8 * gg + 4 * hi + 32) = s1;
    }
    if (hi == 0)
      lsum[(size_t)ck * 65536 + (size_t)qg * 32 + h] = l;

    sbase += nt;
  }
}

// ---------------------------------------------------------------------------
// merge 3 chunk partials in-place into P0 (absolute scale: sum/(l0+l1+l2))
// ---------------------------------------------------------------------------
__global__ __launch_bounds__(256) void attn_merge3(
    u16* __restrict__ P0, const u16* __restrict__ P1, const u16* __restrict__ P2,
    const float* __restrict__ lsum) {
  const int s = blockIdx.x;
  const int e0 = threadIdx.x * 8;
  const int h = e0 >> 6;
  const float l = lsum[(size_t)s * 32 + h] + lsum[65536 + (size_t)s * 32 + h] +
                  lsum[131072 + (size_t)s * 32 + h];
  const float inv = 1.f / l;
  uint4 a = *(const uint4*)(P0 + (size_t)s * 2048 + e0);
  uint4 b = *(const uint4*)(P1 + (size_t)s * 2048 + e0);
  uint4 d = *(const uint4*)(P2 + (size_t)s * 2048 + e0);
  const u16* pa = (const u16*)&a;
  const u16* pb = (const u16*)&b;
  const u16* pd = (const u16*)&d;
  ushort4 oA, oB;
  oA.x = f2bf((bf2f(pa[0]) + bf2f(pb[0]) + bf2f(pd[0])) * inv);
  oA.y = f2bf((bf2f(pa[1]) + bf2f(pb[1]) + bf2f(pd[1])) * inv);
  oA.z = f2bf((bf2f(pa[2]) + bf2f(pb[2]) + bf2f(pd[2])) * inv);
  oA.w = f2bf((bf2f(pa[3]) + bf2f(pb[3]) + bf2f(pd[3])) * inv);
  oB.x = f2bf((bf2f(pa[4]) + bf2f(pb[4]) + bf2f(pd[4])) * inv);
  oB.y = f2bf((bf2f(pa[5]) + bf2f(pb[5]) + bf2f(pd[5])) * inv);
  oB.z = f2bf((bf2f(pa[6]) + bf2f(pb[6]) + bf2f(pd[6])) * inv);
  oB.w = f2bf((bf2f(pa[7]) + bf2f(pb[7]) + bf2f(pd[7])) * inv);
  *(ushort4*)(P0 + (size_t)s * 2048 + e0)     = oA;
  *(ushort4*)(P0 + (size_t)s * 2048 + e0 + 4) = oB;
}

// ---------------------------------------------------------------------------
extern "C" void kernel_launch(void* const* d_in, const int* in_sizes, int n_in,
                              void* d_out, int out_size, void* d_ws, size_t ws_size,
                              hipStream_t stream) {
  const float* X    = (const float*)d_in[0];
  const float* cosp = (const float*)d_in[1];
  const float* sinp = (const float*)d_in[2];
  const float* Wq   = (const float*)d_in[3];
  const float* Wk   = (const float*)d_in[4];
  const float* Wv   = (const float*)d_in[5];
  const float* Wo   = (const float*)d_in[6];

  u16* ws  = (u16*)d_ws;
  u16* Xb  = ws;                         // 2048x2048 (later reused as P0 / ctx)
  u16* Wqb = ws + 4194304;               // 2048x2048 (later reused as P1)
  u16* Wkb = ws + 8388608;               // 512x2048  (later reused as lsum)
  u16* Wvb = ws + 9437184;               // 512x2048
  u16* Wob = ws + 10485760;              // 2048x2048
  u16* Qb  = ws + 14680064;              // 2048x2048 (rope'd, *log2e/8)
  u16* Kb  = ws + 18874368;              // 2048x512  (rope'd)
  u16* Vt  = ws + 19922944;              // 8x64x2048 (V transposed per head)
  u16* P2  = ws + 20971520;              // 2048x2048 chunk-2 partial
  u16* P0  = Xb;
  u16* P1  = Wqb;
  float* lsum = (float*)(ws + 8388608);  // 3 x 2048 x 32 f32

  cvt_all<<<3584, 256, 0, stream>>>(X, Wq, Wk, Wv, Wo, Xb, Wqb, Wkb, Wvb, Wob);

  dim3 gqkv(24, 32), ga(32, 8, 3), go(16, 32);
  gemm_qkv<<<gqkv, 256, 0, stream>>>(Xb, Wqb, Wkb, Wvb, Qb, Kb, Vt, cosp, sinp);
  attn_v9<<<ga, 256, 0, stream>>>(Qb, Kb, Vt, P0, P1, P2, lsum);
  attn_merge3<<<2048, 256, 0, stream>>>(P0, P1, P2, lsum);
  gemm_out<<<go, 256, 0, stream>>>(P0, Wob, (float*)d_out, 2048, 2048, 2048);
}